// Round 5
// baseline (753.037 us; speedup 1.0000x reference)
//
#include <hip/hip_runtime.h>
#include <stdint.h>

// ---------------------------------------------------------------------------
// MambaFormer forward, MI355X/gfx950.  bf16 MFMA (16x16x32) for all GEMMs,
// fp32 accumulation & fp32 LayerNorms.  B=4 S=2048 D=1024 Ds=16 DFF=4096 H=8.
// R9 (resubmit x3): gemm_bt v3b -- 256x128 tile, 512 thr / 8 waves, ring-3
//     LDS (144 KB), BK=64, counted s_waitcnt vmcnt(6) *with lgkmcnt(0)*
//     before each raw s_barrier (closes the pending-ds_read-across-barrier
//     race without draining vmcnt), XOR-swizzled LDS (pre-swizzled global
//     src, linear global_load_lds dst), setprio around MFMA cluster,
//     XCD-chunked bid swizzle.  (T1+T2+T4+T5 from the technique catalog.)
// ---------------------------------------------------------------------------

typedef __bf16 bf16x8 __attribute__((ext_vector_type(8)));
typedef float  floatx4 __attribute__((ext_vector_type(4)));
typedef unsigned short u16;

typedef const __attribute__((address_space(1))) void* gas_t;
typedef __attribute__((address_space(3))) void* las_t;

#define DEV static __device__ __forceinline__

DEV u16 f2bf(float f) {
    unsigned int u;
    __builtin_memcpy(&u, &f, 4);
    u += 0x7fffu + ((u >> 16) & 1u);   // RNE
    return (u16)(u >> 16);
}
DEV float bf2f(u16 h) {
    unsigned int u = ((unsigned int)h) << 16;
    float f; __builtin_memcpy(&f, &u, 4);
    return f;
}
DEV floatx4 mfma16(bf16x8 a, bf16x8 b, floatx4 c) {
    return __builtin_amdgcn_mfma_f32_16x16x32_bf16(a, b, c, 0, 0, 0);
}
DEV float sigmoidf_(float x) { return 1.f / (1.f + __expf(-x)); }

// ---------------------------------------------------------------------------
// Weight transpose + cast: reads in[(rowOff+k)*ldIn + colOff+n] (f32),
// writes out[n*K + k] (bf16).  grid = (N/32, K/32), block = 256.
// ---------------------------------------------------------------------------
__global__ __launch_bounds__(256) void transpose_cast(const float* __restrict__ in,
                                                      u16* __restrict__ out,
                                                      int K, int ldIn,
                                                      int rowOff, int colOff) {
    __shared__ float tile[32][33];
    int bx = blockIdx.x * 32;  // n base
    int by = blockIdx.y * 32;  // k base
    int tx = threadIdx.x & 31, ty = threadIdx.x >> 5;  // ty 0..7
    for (int i = ty; i < 32; i += 8)
        tile[i][tx] = in[(long)(rowOff + by + i) * ldIn + colOff + bx + tx];
    __syncthreads();
    for (int i = ty; i < 32; i += 8)
        out[(long)(bx + i) * K + by + tx] = f2bf(tile[tx][i]);
}

__global__ __launch_bounds__(256) void concat_bias(const float* __restrict__ a,
        const float* __restrict__ b, const float* __restrict__ c,
        float* __restrict__ out) {
    int i = blockIdx.x * 256 + threadIdx.x;   // 0..3071
    float v = (i < 1024) ? a[i] : (i < 2048 ? b[i - 1024] : c[i - 2048]);
    out[i] = v;
}

// ---------------------------------------------------------------------------
// V transpose (bf16): qkv cols [2048..3071] (LD 3072) -> vt[b*8+h][dh=128][S].
// ---------------------------------------------------------------------------
__global__ __launch_bounds__(256) void transpose_v(const u16* __restrict__ qkv,
                                                   u16* __restrict__ vt) {
    __shared__ u16 tile[64][72];
    int s0 = blockIdx.x * 64;
    int d0 = blockIdx.y * 64;
    int bh = blockIdx.z;                 // b*8 + h
    int b = bh >> 3, h = bh & 7;
    int tx = threadIdx.x & 15, ty = threadIdx.x >> 4;   // 16 x 16
    long srcBase = ((long)b * 2048) * 3072 + 2048 + h * 128 + d0;
    for (int i = ty; i < 64; i += 16) {
        ushort4 v4 = *(const ushort4*)(qkv + srcBase + (long)(s0 + i) * 3072 + tx * 4);
        *(ushort4*)&tile[i][tx * 4] = v4;
    }
    __syncthreads();
    long dstBase = ((long)bh * 128 + d0) * 2048 + s0;
    for (int i = ty; i < 64; i += 16) {
        ushort4 o4;
        o4.x = tile[tx * 4 + 0][i];
        o4.y = tile[tx * 4 + 1][i];
        o4.z = tile[tx * 4 + 2][i];
        o4.w = tile[tx * 4 + 3][i];
        *(ushort4*)(vt + dstBase + (long)i * 2048 + tx * 4) = o4;
    }
}

// ---------------------------------------------------------------------------
// Block-wide sum over 1024 cols (256 thr, 4 f32/thr).
// ---------------------------------------------------------------------------
DEV float block_sum(float v, volatile float* red) {
    for (int off = 32; off; off >>= 1) v += __shfl_down(v, off, 64);
    int lane = threadIdx.x & 63, wv = threadIdx.x >> 6;
    if (lane == 0) red[wv] = v;
    __syncthreads();
    return red[0] + red[1] + red[2] + red[3];
}

// Dual LayerNorm of x (shared stats): xn (g0/b0) and xn1 (g1/b1), bf16 out.
__global__ __launch_bounds__(256) void ln_dual_kernel(const float* __restrict__ x,
        const float* __restrict__ g0, const float* __restrict__ b0,
        const float* __restrict__ g1, const float* __restrict__ b1,
        u16* __restrict__ out0, u16* __restrict__ out1) {
    __shared__ float red[8];
    long row = blockIdx.x;
    float4 vx = ((const float4*)(x + row * 1024))[threadIdx.x];
    float s = block_sum(vx.x + vx.y + vx.z + vx.w, red);
    float mean = s * (1.f / 1024.f);
    float dx0 = vx.x - mean, dx1 = vx.y - mean, dx2 = vx.z - mean, dx3 = vx.w - mean;
    float s2 = block_sum(dx0*dx0 + dx1*dx1 + dx2*dx2 + dx3*dx3, red + 4);
    float rs = rsqrtf(s2 * (1.f / 1024.f) + 1e-5f);
    float4 gg = ((const float4*)g0)[threadIdx.x];
    float4 bb = ((const float4*)b0)[threadIdx.x];
    ushort4 o;
    o.x = f2bf(dx0 * rs * gg.x + bb.x); o.y = f2bf(dx1 * rs * gg.y + bb.y);
    o.z = f2bf(dx2 * rs * gg.z + bb.z); o.w = f2bf(dx3 * rs * gg.w + bb.w);
    ((ushort4*)(out0 + row * 1024))[threadIdx.x] = o;
    gg = ((const float4*)g1)[threadIdx.x];
    bb = ((const float4*)b1)[threadIdx.x];
    o.x = f2bf(dx0 * rs * gg.x + bb.x); o.y = f2bf(dx1 * rs * gg.y + bb.y);
    o.z = f2bf(dx2 * rs * gg.z + bb.z); o.w = f2bf(dx3 * rs * gg.w + bb.w);
    ((ushort4*)(out1 + row * 1024))[threadIdx.x] = o;
}

// Single LayerNorm.  OUTBF=1 -> bf16 out, else f32 out (in-place safe).
template <int OUTBF>
__global__ __launch_bounds__(256) void ln_one_kernel(const float* __restrict__ x,
        const float* __restrict__ g, const float* __restrict__ b,
        void* __restrict__ out) {
    __shared__ float red[8];
    long row = blockIdx.x;
    float4 vx = ((const float4*)(x + row * 1024))[threadIdx.x];
    float s = block_sum(vx.x + vx.y + vx.z + vx.w, red);
    float mean = s * (1.f / 1024.f);
    float dx0 = vx.x - mean, dx1 = vx.y - mean, dx2 = vx.z - mean, dx3 = vx.w - mean;
    float s2 = block_sum(dx0*dx0 + dx1*dx1 + dx2*dx2 + dx3*dx3, red + 4);
    float rs = rsqrtf(s2 * (1.f / 1024.f) + 1e-5f);
    float4 gg = ((const float4*)g)[threadIdx.x];
    float4 bb = ((const float4*)b)[threadIdx.x];
    float r0 = dx0 * rs * gg.x + bb.x, r1 = dx1 * rs * gg.y + bb.y;
    float r2 = dx2 * rs * gg.z + bb.z, r3 = dx3 * rs * gg.w + bb.w;
    if (OUTBF) {
        ushort4 o; o.x = f2bf(r0); o.y = f2bf(r1); o.z = f2bf(r2); o.w = f2bf(r3);
        ((ushort4*)((u16*)out + row * 1024))[threadIdx.x] = o;
    } else {
        float4 o; o.x = r0; o.y = r1; o.z = r2; o.w = r3;
        ((float4*)((float*)out + row * 1024))[threadIdx.x] = o;
    }
}

// ---------------------------------------------------------------------------
// delta = sigmoid(xn @ Wdelta + bdelta), Bt = xn @ Win + b_in  via MFMA.
// ---------------------------------------------------------------------------
__global__ __launch_bounds__(256) void delta_bt_kernel(const u16* __restrict__ xn,
        const float* __restrict__ Wd, const float* __restrict__ bd,
        const float* __restrict__ Wi, const float* __restrict__ bi,
        float* __restrict__ delta, float* __restrict__ Bt) {
    __shared__ u16 Wlds[2 * 32 * 64 * 8];   // 64 KB
    int tid = threadIdx.x;
    int wv = tid >> 6, lane = tid & 63;
    int m16 = lane & 15, quad = lane >> 4;

    for (int it = tid; it < 4096; it += 256) {
        int mat = it >> 11, rem = it & 2047;
        int c = rem >> 6, ln = rem & 63;
        int n = ln & 15, q = ln >> 4;
        const float* Wsrc = mat ? Wi : Wd;
        u16 tmp[8];
#pragma unroll
        for (int jj = 0; jj < 8; jj++)
            tmp[jj] = f2bf(Wsrc[(c * 32 + q * 8 + jj) * 16 + n]);
        *(int4*)&Wlds[(long)it * 8] = *(int4*)tmp;
    }
    __syncthreads();

    int row0 = blockIdx.x * 64 + wv * 16;
    floatx4 accD = (floatx4){0.f, 0.f, 0.f, 0.f};
    floatx4 accB = (floatx4){0.f, 0.f, 0.f, 0.f};
#pragma unroll 4
    for (int c = 0; c < 32; c++) {
        bf16x8 afrag = *(const bf16x8*)(xn + (long)(row0 + m16) * 1024 + c * 32 + quad * 8);
        bf16x8 bdv = *(const bf16x8*)&Wlds[(long)(c * 64 + lane) * 8];
        bf16x8 biv = *(const bf16x8*)&Wlds[(long)(2048 + c * 64 + lane) * 8];
        accD = mfma16(afrag, bdv, accD);
        accB = mfma16(afrag, biv, accB);
    }
    float bdd = bd[m16], bii = bi[m16];
#pragma unroll
    for (int r = 0; r < 4; r++) {
        long row = row0 + quad * 4 + r;
        delta[row * 16 + m16] = sigmoidf_(accD[r] + bdd);
        Bt[row * 16 + m16]    = accB[r] + bii;
    }
}

// ---------------------------------------------------------------------------
// Chunk-parallel scan v3: h_t = tanh((h_{t-1}*d_t) @ A + B_t).
// ---------------------------------------------------------------------------
__global__ __launch_bounds__(256) void scan_kernel(const float* __restrict__ delta,
        const float* __restrict__ Bt, const float* __restrict__ A,
        float* __restrict__ h_all) {
    int tid = threadIdx.x;
    int lane = tid & 63, wv = tid >> 6;
    int slotLocal = (wv << 2) + (lane >> 4);
    int s = blockIdx.x * 16 + slotLocal;     // 0..255
    int j = lane & 15;
    int b = s >> 6, chunk = s & 63;
    int t0 = chunk * 32;
    int srcBase = lane & 48;

    float Acol[16];
#pragma unroll
    for (int i = 0; i < 16; i++) Acol[i] = A[i * 16 + j];
    long base = (long)b * 2048 * 16 + j;

    const int W = 16, T = W + 32;            // 48 steps, 12 groups of 4
    float h = 0.f;
    float dbuf[2][4], bbuf[2][4];
#pragma unroll
    for (int u = 0; u < 4; u++) {
        int t = t0 - W + u; if (t < 0) t = 0;
        dbuf[0][u] = delta[base + (long)t * 16];
        bbuf[0][u] = Bt[base + (long)t * 16];
    }
    for (int g = 0; g < T / 4; g++) {
        int cb = g & 1, nb = cb ^ 1;
        if (g + 1 < T / 4) {
#pragma unroll
            for (int u = 0; u < 4; u++) {
                int t = t0 - W + (g + 1) * 4 + u; if (t < 0) t = 0;
                dbuf[nb][u] = delta[base + (long)t * 16];
                bbuf[nb][u] = Bt[base + (long)t * 16];
            }
        }
#pragma unroll
        for (int u = 0; u < 4; u++) {
            int t = t0 - W + g * 4 + u;
            float d = dbuf[cb][u], bt = bbuf[cb][u];
            float gg = h * d;
            float gv[16];
#pragma unroll
            for (int i = 0; i < 16; i++)
                gv[i] = __shfl(gg, srcBase + i, 64);
            float a0 = gv[0] * Acol[0], a1 = gv[1] * Acol[1];
            float a2 = gv[2] * Acol[2], a3 = gv[3] * Acol[3];
#pragma unroll
            for (int i = 4; i < 16; i += 4) {
                a0 += gv[i + 0] * Acol[i + 0];
                a1 += gv[i + 1] * Acol[i + 1];
                a2 += gv[i + 2] * Acol[i + 2];
                a3 += gv[i + 3] * Acol[i + 3];
            }
            float xx = (a0 + a1) + (a2 + a3) + bt;
            xx = fminf(fmaxf(xx, -15.f), 15.f);
            float e = __expf(2.f * xx);
            float hn = (e - 1.f) / (e + 1.f);
            if (t >= 0) h = hn;
            if (t >= t0) h_all[base + (long)t * 16] = h;
        }
    }
}

// ---------------------------------------------------------------------------
// mamba_out = (h_all @ C) * gate + x   -> bf16 into concat[:, 0:1024]
// ---------------------------------------------------------------------------
__global__ __launch_bounds__(256) void mamba_out_kernel(const float* __restrict__ h_all,
        const float* __restrict__ C, const u16* __restrict__ gate,
        const float* __restrict__ x, u16* __restrict__ concat) {
    __shared__ float hs[16];
    long row = blockIdx.x;
    if (threadIdx.x < 16) hs[threadIdx.x] = h_all[row * 16 + threadIdx.x];
    __syncthreads();
    int n = threadIdx.x * 4;
    float a0 = 0.f, a1 = 0.f, a2 = 0.f, a3 = 0.f;
#pragma unroll
    for (int i = 0; i < 16; i++) {
        float hv = hs[i];
        float4 cv = *(const float4*)(C + i * 1024 + n);
        a0 += hv * cv.x; a1 += hv * cv.y; a2 += hv * cv.z; a3 += hv * cv.w;
    }
    ushort4 gv = *(const ushort4*)(gate + row * 1024 + n);
    float4 xv  = *(const float4*)(x + row * 1024 + n);
    ushort4 o;
    o.x = f2bf(a0 * bf2f(gv.x) + xv.x);
    o.y = f2bf(a1 * bf2f(gv.y) + xv.y);
    o.z = f2bf(a2 * bf2f(gv.z) + xv.z);
    o.w = f2bf(a3 * bf2f(gv.w) + xv.w);
    *(ushort4*)(concat + row * 2048 + n) = o;
}

// ---------------------------------------------------------------------------
// Workhorse GEMM v3b:  Out = epi(A[MxK] @ B^T[NxK]^T + bias[n]).
// 256x128 tile, 512 thr / 8 waves (4M x 2N), per-wave 64x64 out (acc[4][4]).
// BK=64.  Ring-3 LDS (3 x {A 32KB + B 16KB} = 144 KB), stage issued 2 tiles
// ahead, raw s_barrier + counted s_waitcnt vmcnt(6) -- loads stay in flight
// across barriers (T4).  lgkmcnt(0) is merged into the pre-barrier wait so
// no wave ever crosses a barrier with LDS reads in flight (closes the
// MFMA-sinking race; costs ~0 since ds_reads are consumed by then).
// Per-wave vmcnt + barrier = collective guarantee: each wave waits for its
// OWN 6 tile-t loads, then the barrier proves ALL waves did -> tile t fully
// resident before any compute(t).
// LDS chunk-XOR swizzle c^=(row&7): write side via pre-swizzled GLOBAL
// source + linear global_load_lds dst, read side same XOR (T2).
// setprio around MFMA (T5), XCD-chunked bid swizzle (T1).
// ACT: 0 none, 1 sigmoid, 2 relu, 3 scale cols<1024 by 1/sqrt(128) (QKV).
// RES: +res[grow*ldRes+gcol] (f32).  OUTF32: f32 out else bf16.
// Requires: M%256==0, N%128==0, K%64==0, K>=192, (gridX*gridY)%8==0.
// ---------------------------------------------------------------------------
#define VM_WAIT_LG(N) asm volatile("s_waitcnt vmcnt(" #N ") lgkmcnt(0)" ::: "memory")

template <int ACT, int RES, int OUTF32>
__global__ __launch_bounds__(512, 2) void gemm_bt(const u16* __restrict__ A,
        const u16* __restrict__ B, const float* __restrict__ bias,
        const float* __restrict__ res, void* __restrict__ Out,
        int M, int N, int K, int ldRes, int ldOut, int colOff) {
    __shared__ __align__(16) u16 smem[3 * 24576];   // 3 x 48 KB
    int tid = threadIdx.x;
    int wv = tid >> 6, lane = tid & 63;
    int wr = wv >> 1, wc = wv & 1;
    int m16 = lane & 15, quad = lane >> 4;
    int swz = m16 & 7;

    // XCD-chunked block swizzle (bijective: nwg % 8 == 0 for all our shapes)
    int nwg = gridDim.x * gridDim.y;
    int bid = blockIdx.y * gridDim.x + blockIdx.x;
    int sw = (bid & 7) * (nwg >> 3) + (bid >> 3);
    int bx = sw % gridDim.x, by = sw / gridDim.x;
    int rowBlk = by * 256, colBlk = bx * 128;

    int trow = tid >> 3;                         // row within a 64-row round
    int schk = ((tid & 7) ^ (trow & 7)) * 8;     // pre-swizzled k-chunk (elems)

    floatx4 acc[4][4];
#pragma unroll
    for (int i = 0; i < 4; i++)
#pragma unroll
        for (int j = 0; j < 4; j++) acc[i][j] = (floatx4){0.f, 0.f, 0.f, 0.f};

    auto stage = [&](int buf, int k0) {
        char* ab = (char*)smem + buf * 49152;
        const u16* gA = A + (long)(rowBlk + trow) * K + k0 + schk;
#pragma unroll
        for (int r = 0; r < 4; r++)
            __builtin_amdgcn_global_load_lds((gas_t)(gA + (long)(r * 64) * K),
                    (las_t)(ab + r * 8192 + wv * 1024), 16, 0, 0);
        const u16* gB = B + (long)(colBlk + trow) * K + k0 + schk;
#pragma unroll
        for (int r = 0; r < 2; r++)
            __builtin_amdgcn_global_load_lds((gas_t)(gB + (long)(r * 64) * K),
                    (las_t)(ab + 32768 + r * 8192 + wv * 1024), 16, 0, 0);
    };

    auto compute = [&](int buf) {
        const u16* Ab = smem + buf * 24576;      // [256][64] (chunk-swizzled)
        const u16* Bb = Ab + 16384;              // [128][64]
#pragma unroll
        for (int kk = 0; kk < 2; kk++) {
            int cs = ((kk * 4 + quad) ^ swz) * 8;
            bf16x8 af[4], bfv[4];
#pragma unroll
            for (int i = 0; i < 4; i++)
                af[i] = *(const bf16x8*)(Ab + (wr * 64 + i * 16 + m16) * 64 + cs);
#pragma unroll
            for (int i = 0; i < 4; i++)
                bfv[i] = *(const bf16x8*)(Bb + (wc * 64 + i * 16 + m16) * 64 + cs);
            __builtin_amdgcn_s_setprio(1);
#pragma unroll
            for (int im = 0; im < 4; im++)
#pragma unroll
                for (int in2 = 0; in2 < 4; in2++)
                    acc[im][in2] = mfma16(af[im], bfv[in2], acc[im][in2]);
            __builtin_amdgcn_s_setprio(0);
        }
    };

    stage(0, 0);
    stage(1, 64);
    int nt = K >> 6;
    int cb = 0, sb = 2;
    for (int t = 0; t < nt - 1; t++) {
        VM_WAIT_LG(6);                   // tile t landed; tile t+1 may fly;
        __builtin_amdgcn_s_barrier();    // no LDS reads in flight past here
        asm volatile("" ::: "memory");
        if (t + 2 < nt) stage(sb, (t + 2) << 6);
        compute(cb);
        cb = (cb == 2) ? 0 : cb + 1;
        sb = (sb == 2) ? 0 : sb + 1;
    }
    VM_WAIT_LG(0);
    __builtin_amdgcn_s_barrier();
    asm volatile("" ::: "memory");
    compute(cb);

#pragma unroll
    for (int in2 = 0; in2 < 4; in2++) {
        int gcol = colBlk + wc * 64 + in2 * 16 + m16;
        float bb = bias ? bias[gcol] : 0.f;
#pragma unroll
        for (int im = 0; im < 4; im++) {
            int growb = rowBlk + wr * 64 + im * 16 + quad * 4;
#pragma unroll
            for (int r = 0; r < 4; r++) {
                float vv = acc[im][in2][r] + bb;
                if (ACT == 1) vv = sigmoidf_(vv);
                if (ACT == 2) vv = fmaxf(vv, 0.f);
                if (ACT == 3 && gcol < 1024) vv *= 0.08838834764831845f;
                long grow = growb + r;
                if (RES) vv += res[grow * ldRes + gcol];
                if (OUTF32) ((float*)Out)[grow * ldOut + colOff + gcol] = vv;
                else        ((u16*)Out)[grow * ldOut + colOff + gcol] = f2bf(vv);
            }
        }
    }
}

// ---------------------------------------------------------------------------
// Flash attention v4 (validated R6).  Grid 512 1-D, XCD swizzle.
// ---------------------------------------------------------------------------
__global__ __launch_bounds__(256, 2) void flash_attn(const u16* __restrict__ qkv,
        const u16* __restrict__ vt, u16* __restrict__ ctx) {
    constexpr int S = 2048, HD = 128, KT = 64, LD = 3072;
    __shared__ u16 Ks[2][KT * 128];
    __shared__ u16 Vt[2][HD * 64];
    __shared__ u16 Pa[128 * 64];

    int bid = blockIdx.x;
    int bh = ((bid & 7) << 2) | ((bid >> 3) & 3);
    int qt = bid >> 5;
    int b = bh >> 3, h = bh & 7;
    int tid = threadIdx.x, wv = tid >> 6, lane = tid & 63;
    int m16 = lane & 15, quad = lane >> 4;
    long rowBase = (long)b * S;
    const u16* kptr = qkv + 1024 + h * HD;
    const u16* vptr = vt + (long)bh * HD * S;

    int kLR = lane >> 4, kCk = lane & 15;
    int vLR = lane >> 3, vCk = lane & 7;

    bf16x8 qf[2][4];
    int qrow0 = qt * 128 + wv * 32;
#pragma unroll
    for (int mt = 0; mt < 2; mt++)
#pragma unroll
        for (int kc = 0; kc < 4; kc++)
            qf[mt][kc] = *(const bf16x8*)(qkv + (rowBase + qrow0 + mt * 16 + m16) * LD
                                            + h * HD + kc * 32 + quad * 8);

    floatx4 o[2][8];
#pragma unroll
    for (int mt = 0; mt < 2; mt++)
#pragma unroll
        for (int dt = 0; dt < 8; dt++) o[mt][dt] = (floatx4){0.f, 0.f, 0.f, 0.f};
    float lsum[2][4];
#pragma unroll
    for (int mt = 0; mt < 2; mt++)
#pragma unroll
        for (int r = 0; r < 4; r++) lsum[mt][r] = 0.f;

    auto stage = [&](int buf, int krow0) {
#pragma unroll
        for (int it = 0; it < 4; it++) {
            int grl = wv * 16 + it * 4 + kLR;
            int gc = (kCk & 8) | ((kCk ^ grl) & 7);
            const u16* gK = kptr + (rowBase + krow0 + grl) * LD + gc * 8;
            __builtin_amdgcn_global_load_lds((gas_t)gK,
                    (las_t)&Ks[buf][(wv * 16 + it * 4) * 128], 16, 0, 0);
            int gvl = wv * 32 + it * 8 + vLR;
            int gvc = vCk ^ (gvl & 7);
            const u16* gV = vptr + (long)gvl * S + krow0 + gvc * 8;
            __builtin_amdgcn_global_load_lds((gas_t)gV,
                    (las_t)&Vt[buf][(wv * 32 + it * 8) * 64], 16, 0, 0);
        }
    };

    stage(0, 0);
    for (int kt = 0; kt < S / KT; kt++) {
        int cur = kt & 1;
        __syncthreads();
        if (kt + 1 < S / KT) stage(cur ^ 1, (kt + 1) * KT);

        floatx4 sacc[2][4];
#pragma unroll
        for (int mt = 0; mt < 2; mt++)
#pragma unroll
            for (int nt = 0; nt < 4; nt++) sacc[mt][nt] = (floatx4){0.f, 0.f, 0.f, 0.f};
#pragma unroll
        for (int nt = 0; nt < 4; nt++)
#pragma unroll
            for (int kc = 0; kc < 4; kc++) {
                int c = kc * 4 + quad;
                int csw = (c & 8) | ((c ^ m16) & 7);
                bf16x8 kf = *(const bf16x8*)&Ks[cur][(nt * 16 + m16) * 128 + csw * 8];
                sacc[0][nt] = mfma16(qf[0][kc], kf, sacc[0][nt]);
                sacc[1][nt] = mfma16(qf[1][kc], kf, sacc[1][nt]);
            }

#pragma unroll
        for (int mt = 0; mt < 2; mt++)
#pragma unroll
            for (int r = 0; r < 4; r++) {
                float ps = 0.f;
#pragma unroll
                for (int nt = 0; nt < 4; nt++) {
                    float pp = __expf(sacc[mt][nt][r]);
                    sacc[mt][nt][r] = pp;
                    ps += pp;
                }
                lsum[mt][r] += ps;
            }

#pragma unroll
        for (int mt = 0; mt < 2; mt++)
#pragma unroll
            for (int nt = 0; nt < 4; nt++)
#pragma unroll
                for (int r = 0; r < 4; r++) {
                    int qr = quad * 4 + r;
                    int c = nt * 2 + (m16 >> 3);
                    Pa[(wv * 32 + mt * 16 + qr) * 64 + ((c ^ (qr & 7)) * 8) + (m16 & 7)] =
                        f2bf(sacc[mt][nt][r]);
                }

        bf16x8 pf[2][2];
#pragma unroll
        for (int mt = 0; mt < 2; mt++)
#pragma unroll
            for (int kc = 0; kc < 2; kc++) {
                int c = kc * 4 + quad;
                int csw = (c ^ m16) & 7;
                pf[mt][kc] = *(const bf16x8*)&Pa[(wv * 32 + mt * 16 + m16) * 64 + csw * 8];
            }
#pragma unroll
        for (int dt = 0; dt < 8; dt++)
#pragma unroll
            for (int kc = 0; kc < 2; kc++) {
                int c = kc * 4 + quad;
                int csw = (c ^ m16) & 7;
                bf16x8 vf = *(const bf16x8*)&Vt[cur][(dt * 16 + m16) * 64 + csw * 8];
                o[0][dt] = mfma16(pf[0][kc], vf, o[0][dt]);
                o[1][dt] = mfma16(pf[1][kc], vf, o[1][dt]);
            }
    }

#pragma unroll
    for (int mt = 0; mt < 2; mt++) {
        float linv[4];
#pragma unroll
        for (int r = 0; r < 4; r++) {
            float rs = lsum[mt][r];
#pragma unroll
            for (int off = 1; off < 16; off <<= 1)
                rs += __shfl_xor(rs, off, 64);
            linv[r] = 1.f / rs;
        }
#pragma unroll
        for (int dt = 0; dt < 8; dt++)
#pragma unroll
            for (int r = 0; r < 4; r++) {
                float val = o[mt][dt][r] * linv[r];
                long grow = qt * 128 + wv * 32 + mt * 16 + quad * 4 + r;
                ctx[(rowBase + grow) * 1024 + h * HD + dt * 16 + m16] = f2bf(val);
            }
    }
}

// ---------------------------------------------------------------------------
// Launch.  Workspace map (MB offsets, lifetimes serial on stream):
//   [  0, 32) conc (u16 8192x2048)
//   [ 32, 48) slot1: xn -> ctx -> xn2
//   [ 48, 64) xn1 -> vt (16 MB) -> ffn1h low half
//   [ 64,112) gate (64..80) -> qkv (48 MB) -> {ffn1h high [64,80), x2 [80,112)}
//   [112,118) wscr: transposed weights (max 6 MB, merged QKV)
//   [118,~120) bias3 + delta + Btb + h_all
// ---------------------------------------------------------------------------
extern "C" void kernel_launch(void* const* d_in, const int* in_sizes, int n_in,
                              void* d_out, int out_size, void* d_ws, size_t ws_size,
                              hipStream_t stream) {
    (void)in_sizes; (void)n_in; (void)out_size; (void)ws_size;
    const float* x      = (const float*)d_in[0];
    const float* ln_g   = (const float*)d_in[1];
    const float* ln_b   = (const float*)d_in[2];
    const float* Wdelta = (const float*)d_in[3];
    const float* bdelta = (const float*)d_in[4];
    const float* Win    = (const float*)d_in[5];
    const float* b_in   = (const float*)d_in[6];
    const float* Wgate  = (const float*)d_in[7];
    const float* bgate  = (const float*)d_in[8];
    const float* Amat   = (const float*)d_in[9];
    const float* Cmat   = (const float*)d_in[10];
    const float* ln1_g  = (const float*)d_in[11];
    const float* ln1_b  = (const float*)d_in[12];
    const float* Wq     = (const float*)d_in[13];
    const float* bq     = (const float*)d_in[14];
    const float* Wk     = (const float*)d_in[15];
    const float* bk     = (const float*)d_in[16];
    const float* Wv     = (const float*)d_in[17];
    const float* bv     = (const float*)d_in[18];
    const float* Wo     = (const float*)d_in[19];
    const float* bo     = (const float*)d_in[20];
    const float* ln2_g  = (const float*)d_in[21];
    const float* ln2_b  = (const float*)d_in[22];
    const float* W1     = (const float*)d_in[23];
    const float* b1     = (const float*)d_in[24];
    const float* W2     = (const float*)d_in[25];
    const float* b2     = (const float*)d_in[26];
    const float* Wf     = (const float*)d_in[27];
    const float* bfp    = (const float*)d_in[28];
    const float* lnf_g  = (const float*)d_in[29];
    const float* lnf_b  = (const float*)d_in[30];

    char* base = (char*)d_ws;
    const size_t MB = 1u << 20;
    u16*   conc  = (u16*)(base + 0 * MB);
    u16*   slot1 = (u16*)(base + 32 * MB);
    u16*   xn1   = (u16*)(base + 48 * MB);
    u16*   qkv   = (u16*)(base + 64 * MB);
    u16*   wscr  = (u16*)(base + 112 * MB);
    float* bias3 = (float*)(base + 118 * MB);
    float* delta = (float*)(base + 118 * MB + 512 * 1024);
    float* Btb   = (float*)(base + 119 * MB);
    float* h_all = (float*)(base + 119 * MB + 512 * 1024);

    u16* xn    = slot1;
    u16* gate  = qkv;                        // dead before qkv written
    u16* ctx   = slot1;
    u16* xn2   = slot1;
    u16* vt    = xn1;                        // 16 MB, after xn1 consumed
    u16* ffn1h = xn1;                        // 32 MB: [48,80)
    float* x2  = (float*)(base + 80 * MB);   // 32 MB f32: [80,112)

    // 1) dual LN
    ln_dual_kernel<<<8192, 256, 0, stream>>>(x, ln_g, ln_b, ln1_g, ln1_b, xn, xn1);

    // 2) mamba projections (MFMA) + chunk-parallel scan
    delta_bt_kernel<<<128, 256, 0, stream>>>(xn, Wdelta, bdelta, Win, b_in, delta, Btb);
    scan_kernel<<<16, 256, 0, stream>>>(delta, Btb, Amat, h_all);

    // 3) gate = sigmoid(xn @ Wgate + bgate)   (256 WGs)
    transpose_cast<<<dim3(32, 32), 256, 0, stream>>>(Wgate, wscr, 1024, 1024, 0, 0);
    gemm_bt<1, 0, 0><<<dim3(8, 32), 512, 0, stream>>>(xn, wscr, bgate, nullptr,
            gate, 8192, 1024, 1024, 0, 1024, 0);
    // 4) mamba_out -> concat[:, :1024]
    mamba_out_kernel<<<8192, 256, 0, stream>>>(h_all, Cmat, gate, x, conc);

    // 5) merged QKV (Q cols pre-scaled by 1/sqrt(128) in epilogue, ACT=3) (768 WGs)
    transpose_cast<<<dim3(32, 32), 256, 0, stream>>>(Wq, wscr, 1024, 1024, 0, 0);
    transpose_cast<<<dim3(32, 32), 256, 0, stream>>>(Wk, wscr + 1024 * 1024, 1024, 1024, 0, 0);
    transpose_cast<<<dim3(32, 32), 256, 0, stream>>>(Wv, wscr + 2 * 1024 * 1024, 1024, 1024, 0, 0);
    concat_bias<<<12, 256, 0, stream>>>(bq, bk, bv, bias3);
    gemm_bt<3, 0, 0><<<dim3(24, 32), 512, 0, stream>>>(xn1, wscr, bias3, nullptr,
            qkv, 8192, 3072, 1024, 0, 3072, 0);

    // 5b) V -> vt[bh][dh][S] (xn1 dead after QKV GEMM)
    transpose_v<<<dim3(32, 2, 32), 256, 0, stream>>>(qkv, vt);

    // 6) attention (ctx overwrites xn in slot1)
    flash_attn<<<512, 256, 0, stream>>>(qkv, vt, ctx);

    // 7) x2 = x + ctx @ Wo + bo (f32; overwrites dead parts of qkv)
    transpose_cast<<<dim3(32, 32), 256, 0, stream>>>(Wo, wscr, 1024, 1024, 0, 0);
    gemm_bt<0, 1, 1><<<dim3(8, 32), 512, 0, stream>>>(ctx, wscr, bo, x,
            x2, 8192, 1024, 1024, 1024, 1024, 0);

    // 8) xn2 = LN(x2) -> bf16 (overwrites ctx)
    ln_one_kernel<1><<<8192, 256, 0, stream>>>(x2, ln2_g, ln2_b, xn2);

    // 9) FFN in two N-halves (ffn1h 32 MB reused)   (512 / 256 WGs)
    transpose_cast<<<dim3(64, 32), 256, 0, stream>>>(W1, wscr, 1024, 4096, 0, 0);
    gemm_bt<2, 0, 0><<<dim3(16, 32), 512, 0, stream>>>(xn2, wscr, b1, nullptr,
            ffn1h, 8192, 2048, 1024, 0, 2048, 0);
    transpose_cast<<<dim3(32, 64), 256, 0, stream>>>(W2, wscr, 2048, 1024, 0, 0);
    gemm_bt<0, 1, 1><<<dim3(8, 32), 512, 0, stream>>>(ffn1h, wscr, b2, x2,
            x2, 8192, 1024, 2048, 1024, 1024, 0);
    transpose_cast<<<dim3(64, 32), 256, 0, stream>>>(W1, wscr, 1024, 4096, 0, 2048);
    gemm_bt<2, 0, 0><<<dim3(16, 32), 512, 0, stream>>>(xn2, wscr, b1 + 2048, nullptr,
            ffn1h, 8192, 2048, 1024, 0, 2048, 0);
    transpose_cast<<<dim3(32, 64), 256, 0, stream>>>(W2, wscr, 2048, 1024, 2048, 0);
    gemm_bt<0, 1, 0><<<dim3(8, 32), 512, 0, stream>>>(ffn1h, wscr, nullptr, x2,
            conc, 8192, 1024, 2048, 1024, 2048, 1024);

    // 10) fused_pre = concat @ Wf + bf  (K=2048, f32 into d_out)
    transpose_cast<<<dim3(32, 64), 256, 0, stream>>>(Wf, wscr, 2048, 1024, 0, 0);
    gemm_bt<0, 0, 1><<<dim3(8, 32), 512, 0, stream>>>(conc, wscr, bfp, nullptr,
            (float*)d_out, 8192, 1024, 2048, 0, 1024, 0);

    // 11) final LN in place on d_out (f32)
    ln_one_kernel<0><<<8192, 256, 0, stream>>>((const float*)d_out, lnf_g, lnf_b, d_out);
}

// Round 6
// 748.531 us; speedup vs baseline: 1.0060x; 1.0060x over previous
//
#include <hip/hip_runtime.h>
#include <stdint.h>

// ---------------------------------------------------------------------------
// MambaFormer forward, MI355X/gfx950.  bf16 MFMA (16x16x32) for all GEMMs,
// fp32 accumulation & fp32 LayerNorms.  B=4 S=2048 D=1024 Ds=16 DFF=4096 H=8.
// R10: flash_attn v5 -- 8 waves x 16 q-rows (512 thr), same 80 KB LDS and
//     grid 512; 2 blocks/CU now carry 16 waves/CU (4/SIMD, was 2/SIMD).
//     Halved per-wave register state; all LDS swizzles preserved.
//     gemm_bt v3b (verified R9, 753 us total) unchanged.
// ---------------------------------------------------------------------------

typedef __bf16 bf16x8 __attribute__((ext_vector_type(8)));
typedef float  floatx4 __attribute__((ext_vector_type(4)));
typedef unsigned short u16;

typedef const __attribute__((address_space(1))) void* gas_t;
typedef __attribute__((address_space(3))) void* las_t;

#define DEV static __device__ __forceinline__

DEV u16 f2bf(float f) {
    unsigned int u;
    __builtin_memcpy(&u, &f, 4);
    u += 0x7fffu + ((u >> 16) & 1u);   // RNE
    return (u16)(u >> 16);
}
DEV float bf2f(u16 h) {
    unsigned int u = ((unsigned int)h) << 16;
    float f; __builtin_memcpy(&f, &u, 4);
    return f;
}
DEV floatx4 mfma16(bf16x8 a, bf16x8 b, floatx4 c) {
    return __builtin_amdgcn_mfma_f32_16x16x32_bf16(a, b, c, 0, 0, 0);
}
DEV float sigmoidf_(float x) { return 1.f / (1.f + __expf(-x)); }

// ---------------------------------------------------------------------------
// Weight transpose + cast: reads in[(rowOff+k)*ldIn + colOff+n] (f32),
// writes out[n*K + k] (bf16).  grid = (N/32, K/32), block = 256.
// ---------------------------------------------------------------------------
__global__ __launch_bounds__(256) void transpose_cast(const float* __restrict__ in,
                                                      u16* __restrict__ out,
                                                      int K, int ldIn,
                                                      int rowOff, int colOff) {
    __shared__ float tile[32][33];
    int bx = blockIdx.x * 32;  // n base
    int by = blockIdx.y * 32;  // k base
    int tx = threadIdx.x & 31, ty = threadIdx.x >> 5;  // ty 0..7
    for (int i = ty; i < 32; i += 8)
        tile[i][tx] = in[(long)(rowOff + by + i) * ldIn + colOff + bx + tx];
    __syncthreads();
    for (int i = ty; i < 32; i += 8)
        out[(long)(bx + i) * K + by + tx] = f2bf(tile[tx][i]);
}

__global__ __launch_bounds__(256) void concat_bias(const float* __restrict__ a,
        const float* __restrict__ b, const float* __restrict__ c,
        float* __restrict__ out) {
    int i = blockIdx.x * 256 + threadIdx.x;   // 0..3071
    float v = (i < 1024) ? a[i] : (i < 2048 ? b[i - 1024] : c[i - 2048]);
    out[i] = v;
}

// ---------------------------------------------------------------------------
// V transpose (bf16): qkv cols [2048..3071] (LD 3072) -> vt[b*8+h][dh=128][S].
// ---------------------------------------------------------------------------
__global__ __launch_bounds__(256) void transpose_v(const u16* __restrict__ qkv,
                                                   u16* __restrict__ vt) {
    __shared__ u16 tile[64][72];
    int s0 = blockIdx.x * 64;
    int d0 = blockIdx.y * 64;
    int bh = blockIdx.z;                 // b*8 + h
    int b = bh >> 3, h = bh & 7;
    int tx = threadIdx.x & 15, ty = threadIdx.x >> 4;   // 16 x 16
    long srcBase = ((long)b * 2048) * 3072 + 2048 + h * 128 + d0;
    for (int i = ty; i < 64; i += 16) {
        ushort4 v4 = *(const ushort4*)(qkv + srcBase + (long)(s0 + i) * 3072 + tx * 4);
        *(ushort4*)&tile[i][tx * 4] = v4;
    }
    __syncthreads();
    long dstBase = ((long)bh * 128 + d0) * 2048 + s0;
    for (int i = ty; i < 64; i += 16) {
        ushort4 o4;
        o4.x = tile[tx * 4 + 0][i];
        o4.y = tile[tx * 4 + 1][i];
        o4.z = tile[tx * 4 + 2][i];
        o4.w = tile[tx * 4 + 3][i];
        *(ushort4*)(vt + dstBase + (long)i * 2048 + tx * 4) = o4;
    }
}

// ---------------------------------------------------------------------------
// Block-wide sum over 1024 cols (256 thr, 4 f32/thr).
// ---------------------------------------------------------------------------
DEV float block_sum(float v, volatile float* red) {
    for (int off = 32; off; off >>= 1) v += __shfl_down(v, off, 64);
    int lane = threadIdx.x & 63, wv = threadIdx.x >> 6;
    if (lane == 0) red[wv] = v;
    __syncthreads();
    return red[0] + red[1] + red[2] + red[3];
}

// Dual LayerNorm of x (shared stats): xn (g0/b0) and xn1 (g1/b1), bf16 out.
__global__ __launch_bounds__(256) void ln_dual_kernel(const float* __restrict__ x,
        const float* __restrict__ g0, const float* __restrict__ b0,
        const float* __restrict__ g1, const float* __restrict__ b1,
        u16* __restrict__ out0, u16* __restrict__ out1) {
    __shared__ float red[8];
    long row = blockIdx.x;
    float4 vx = ((const float4*)(x + row * 1024))[threadIdx.x];
    float s = block_sum(vx.x + vx.y + vx.z + vx.w, red);
    float mean = s * (1.f / 1024.f);
    float dx0 = vx.x - mean, dx1 = vx.y - mean, dx2 = vx.z - mean, dx3 = vx.w - mean;
    float s2 = block_sum(dx0*dx0 + dx1*dx1 + dx2*dx2 + dx3*dx3, red + 4);
    float rs = rsqrtf(s2 * (1.f / 1024.f) + 1e-5f);
    float4 gg = ((const float4*)g0)[threadIdx.x];
    float4 bb = ((const float4*)b0)[threadIdx.x];
    ushort4 o;
    o.x = f2bf(dx0 * rs * gg.x + bb.x); o.y = f2bf(dx1 * rs * gg.y + bb.y);
    o.z = f2bf(dx2 * rs * gg.z + bb.z); o.w = f2bf(dx3 * rs * gg.w + bb.w);
    ((ushort4*)(out0 + row * 1024))[threadIdx.x] = o;
    gg = ((const float4*)g1)[threadIdx.x];
    bb = ((const float4*)b1)[threadIdx.x];
    o.x = f2bf(dx0 * rs * gg.x + bb.x); o.y = f2bf(dx1 * rs * gg.y + bb.y);
    o.z = f2bf(dx2 * rs * gg.z + bb.z); o.w = f2bf(dx3 * rs * gg.w + bb.w);
    ((ushort4*)(out1 + row * 1024))[threadIdx.x] = o;
}

// Single LayerNorm.  OUTBF=1 -> bf16 out, else f32 out (in-place safe).
template <int OUTBF>
__global__ __launch_bounds__(256) void ln_one_kernel(const float* __restrict__ x,
        const float* __restrict__ g, const float* __restrict__ b,
        void* __restrict__ out) {
    __shared__ float red[8];
    long row = blockIdx.x;
    float4 vx = ((const float4*)(x + row * 1024))[threadIdx.x];
    float s = block_sum(vx.x + vx.y + vx.z + vx.w, red);
    float mean = s * (1.f / 1024.f);
    float dx0 = vx.x - mean, dx1 = vx.y - mean, dx2 = vx.z - mean, dx3 = vx.w - mean;
    float s2 = block_sum(dx0*dx0 + dx1*dx1 + dx2*dx2 + dx3*dx3, red + 4);
    float rs = rsqrtf(s2 * (1.f / 1024.f) + 1e-5f);
    float4 gg = ((const float4*)g)[threadIdx.x];
    float4 bb = ((const float4*)b)[threadIdx.x];
    float r0 = dx0 * rs * gg.x + bb.x, r1 = dx1 * rs * gg.y + bb.y;
    float r2 = dx2 * rs * gg.z + bb.z, r3 = dx3 * rs * gg.w + bb.w;
    if (OUTBF) {
        ushort4 o; o.x = f2bf(r0); o.y = f2bf(r1); o.z = f2bf(r2); o.w = f2bf(r3);
        ((ushort4*)((u16*)out + row * 1024))[threadIdx.x] = o;
    } else {
        float4 o; o.x = r0; o.y = r1; o.z = r2; o.w = r3;
        ((float4*)((float*)out + row * 1024))[threadIdx.x] = o;
    }
}

// ---------------------------------------------------------------------------
// delta = sigmoid(xn @ Wdelta + bdelta), Bt = xn @ Win + b_in  via MFMA.
// ---------------------------------------------------------------------------
__global__ __launch_bounds__(256) void delta_bt_kernel(const u16* __restrict__ xn,
        const float* __restrict__ Wd, const float* __restrict__ bd,
        const float* __restrict__ Wi, const float* __restrict__ bi,
        float* __restrict__ delta, float* __restrict__ Bt) {
    __shared__ u16 Wlds[2 * 32 * 64 * 8];   // 64 KB
    int tid = threadIdx.x;
    int wv = tid >> 6, lane = tid & 63;
    int m16 = lane & 15, quad = lane >> 4;

    for (int it = tid; it < 4096; it += 256) {
        int mat = it >> 11, rem = it & 2047;
        int c = rem >> 6, ln = rem & 63;
        int n = ln & 15, q = ln >> 4;
        const float* Wsrc = mat ? Wi : Wd;
        u16 tmp[8];
#pragma unroll
        for (int jj = 0; jj < 8; jj++)
            tmp[jj] = f2bf(Wsrc[(c * 32 + q * 8 + jj) * 16 + n]);
        *(int4*)&Wlds[(long)it * 8] = *(int4*)tmp;
    }
    __syncthreads();

    int row0 = blockIdx.x * 64 + wv * 16;
    floatx4 accD = (floatx4){0.f, 0.f, 0.f, 0.f};
    floatx4 accB = (floatx4){0.f, 0.f, 0.f, 0.f};
#pragma unroll 4
    for (int c = 0; c < 32; c++) {
        bf16x8 afrag = *(const bf16x8*)(xn + (long)(row0 + m16) * 1024 + c * 32 + quad * 8);
        bf16x8 bdv = *(const bf16x8*)&Wlds[(long)(c * 64 + lane) * 8];
        bf16x8 biv = *(const bf16x8*)&Wlds[(long)(2048 + c * 64 + lane) * 8];
        accD = mfma16(afrag, bdv, accD);
        accB = mfma16(afrag, biv, accB);
    }
    float bdd = bd[m16], bii = bi[m16];
#pragma unroll
    for (int r = 0; r < 4; r++) {
        long row = row0 + quad * 4 + r;
        delta[row * 16 + m16] = sigmoidf_(accD[r] + bdd);
        Bt[row * 16 + m16]    = accB[r] + bii;
    }
}

// ---------------------------------------------------------------------------
// Chunk-parallel scan v3: h_t = tanh((h_{t-1}*d_t) @ A + B_t).
// ---------------------------------------------------------------------------
__global__ __launch_bounds__(256) void scan_kernel(const float* __restrict__ delta,
        const float* __restrict__ Bt, const float* __restrict__ A,
        float* __restrict__ h_all) {
    int tid = threadIdx.x;
    int lane = tid & 63, wv = tid >> 6;
    int slotLocal = (wv << 2) + (lane >> 4);
    int s = blockIdx.x * 16 + slotLocal;     // 0..255
    int j = lane & 15;
    int b = s >> 6, chunk = s & 63;
    int t0 = chunk * 32;
    int srcBase = lane & 48;

    float Acol[16];
#pragma unroll
    for (int i = 0; i < 16; i++) Acol[i] = A[i * 16 + j];
    long base = (long)b * 2048 * 16 + j;

    const int W = 16, T = W + 32;            // 48 steps, 12 groups of 4
    float h = 0.f;
    float dbuf[2][4], bbuf[2][4];
#pragma unroll
    for (int u = 0; u < 4; u++) {
        int t = t0 - W + u; if (t < 0) t = 0;
        dbuf[0][u] = delta[base + (long)t * 16];
        bbuf[0][u] = Bt[base + (long)t * 16];
    }
    for (int g = 0; g < T / 4; g++) {
        int cb = g & 1, nb = cb ^ 1;
        if (g + 1 < T / 4) {
#pragma unroll
            for (int u = 0; u < 4; u++) {
                int t = t0 - W + (g + 1) * 4 + u; if (t < 0) t = 0;
                dbuf[nb][u] = delta[base + (long)t * 16];
                bbuf[nb][u] = Bt[base + (long)t * 16];
            }
        }
#pragma unroll
        for (int u = 0; u < 4; u++) {
            int t = t0 - W + g * 4 + u;
            float d = dbuf[cb][u], bt = bbuf[cb][u];
            float gg = h * d;
            float gv[16];
#pragma unroll
            for (int i = 0; i < 16; i++)
                gv[i] = __shfl(gg, srcBase + i, 64);
            float a0 = gv[0] * Acol[0], a1 = gv[1] * Acol[1];
            float a2 = gv[2] * Acol[2], a3 = gv[3] * Acol[3];
#pragma unroll
            for (int i = 4; i < 16; i += 4) {
                a0 += gv[i + 0] * Acol[i + 0];
                a1 += gv[i + 1] * Acol[i + 1];
                a2 += gv[i + 2] * Acol[i + 2];
                a3 += gv[i + 3] * Acol[i + 3];
            }
            float xx = (a0 + a1) + (a2 + a3) + bt;
            xx = fminf(fmaxf(xx, -15.f), 15.f);
            float e = __expf(2.f * xx);
            float hn = (e - 1.f) / (e + 1.f);
            if (t >= 0) h = hn;
            if (t >= t0) h_all[base + (long)t * 16] = h;
        }
    }
}

// ---------------------------------------------------------------------------
// mamba_out = (h_all @ C) * gate + x   -> bf16 into concat[:, 0:1024]
// ---------------------------------------------------------------------------
__global__ __launch_bounds__(256) void mamba_out_kernel(const float* __restrict__ h_all,
        const float* __restrict__ C, const u16* __restrict__ gate,
        const float* __restrict__ x, u16* __restrict__ concat) {
    __shared__ float hs[16];
    long row = blockIdx.x;
    if (threadIdx.x < 16) hs[threadIdx.x] = h_all[row * 16 + threadIdx.x];
    __syncthreads();
    int n = threadIdx.x * 4;
    float a0 = 0.f, a1 = 0.f, a2 = 0.f, a3 = 0.f;
#pragma unroll
    for (int i = 0; i < 16; i++) {
        float hv = hs[i];
        float4 cv = *(const float4*)(C + i * 1024 + n);
        a0 += hv * cv.x; a1 += hv * cv.y; a2 += hv * cv.z; a3 += hv * cv.w;
    }
    ushort4 gv = *(const ushort4*)(gate + row * 1024 + n);
    float4 xv  = *(const float4*)(x + row * 1024 + n);
    ushort4 o;
    o.x = f2bf(a0 * bf2f(gv.x) + xv.x);
    o.y = f2bf(a1 * bf2f(gv.y) + xv.y);
    o.z = f2bf(a2 * bf2f(gv.z) + xv.z);
    o.w = f2bf(a3 * bf2f(gv.w) + xv.w);
    *(ushort4*)(concat + row * 2048 + n) = o;
}

// ---------------------------------------------------------------------------
// Workhorse GEMM v3b (verified R9):  Out = epi(A[MxK] @ B^T[NxK]^T + bias).
// 256x128 tile, 512 thr / 8 waves, ring-3 LDS, BK=64, counted
// s_waitcnt vmcnt(6) lgkmcnt(0) + raw s_barrier, XOR-swizzled LDS,
// setprio, XCD-chunked bid swizzle.  UNCHANGED from the 753 us run.
// ---------------------------------------------------------------------------
#define VM_WAIT_LG(N) asm volatile("s_waitcnt vmcnt(" #N ") lgkmcnt(0)" ::: "memory")

template <int ACT, int RES, int OUTF32>
__global__ __launch_bounds__(512, 2) void gemm_bt(const u16* __restrict__ A,
        const u16* __restrict__ B, const float* __restrict__ bias,
        const float* __restrict__ res, void* __restrict__ Out,
        int M, int N, int K, int ldRes, int ldOut, int colOff) {
    __shared__ __align__(16) u16 smem[3 * 24576];   // 3 x 48 KB
    int tid = threadIdx.x;
    int wv = tid >> 6, lane = tid & 63;
    int wr = wv >> 1, wc = wv & 1;
    int m16 = lane & 15, quad = lane >> 4;
    int swz = m16 & 7;

    int nwg = gridDim.x * gridDim.y;
    int bid = blockIdx.y * gridDim.x + blockIdx.x;
    int sw = (bid & 7) * (nwg >> 3) + (bid >> 3);
    int bx = sw % gridDim.x, by = sw / gridDim.x;
    int rowBlk = by * 256, colBlk = bx * 128;

    int trow = tid >> 3;                         // row within a 64-row round
    int schk = ((tid & 7) ^ (trow & 7)) * 8;     // pre-swizzled k-chunk (elems)

    floatx4 acc[4][4];
#pragma unroll
    for (int i = 0; i < 4; i++)
#pragma unroll
        for (int j = 0; j < 4; j++) acc[i][j] = (floatx4){0.f, 0.f, 0.f, 0.f};

    auto stage = [&](int buf, int k0) {
        char* ab = (char*)smem + buf * 49152;
        const u16* gA = A + (long)(rowBlk + trow) * K + k0 + schk;
#pragma unroll
        for (int r = 0; r < 4; r++)
            __builtin_amdgcn_global_load_lds((gas_t)(gA + (long)(r * 64) * K),
                    (las_t)(ab + r * 8192 + wv * 1024), 16, 0, 0);
        const u16* gB = B + (long)(colBlk + trow) * K + k0 + schk;
#pragma unroll
        for (int r = 0; r < 2; r++)
            __builtin_amdgcn_global_load_lds((gas_t)(gB + (long)(r * 64) * K),
                    (las_t)(ab + 32768 + r * 8192 + wv * 1024), 16, 0, 0);
    };

    auto compute = [&](int buf) {
        const u16* Ab = smem + buf * 24576;      // [256][64] (chunk-swizzled)
        const u16* Bb = Ab + 16384;              // [128][64]
#pragma unroll
        for (int kk = 0; kk < 2; kk++) {
            int cs = ((kk * 4 + quad) ^ swz) * 8;
            bf16x8 af[4], bfv[4];
#pragma unroll
            for (int i = 0; i < 4; i++)
                af[i] = *(const bf16x8*)(Ab + (wr * 64 + i * 16 + m16) * 64 + cs);
#pragma unroll
            for (int i = 0; i < 4; i++)
                bfv[i] = *(const bf16x8*)(Bb + (wc * 64 + i * 16 + m16) * 64 + cs);
            __builtin_amdgcn_s_setprio(1);
#pragma unroll
            for (int im = 0; im < 4; im++)
#pragma unroll
                for (int in2 = 0; in2 < 4; in2++)
                    acc[im][in2] = mfma16(af[im], bfv[in2], acc[im][in2]);
            __builtin_amdgcn_s_setprio(0);
        }
    };

    stage(0, 0);
    stage(1, 64);
    int nt = K >> 6;
    int cb = 0, sb = 2;
    for (int t = 0; t < nt - 1; t++) {
        VM_WAIT_LG(6);                   // tile t landed; tile t+1 may fly;
        __builtin_amdgcn_s_barrier();    // no LDS reads in flight past here
        asm volatile("" ::: "memory");
        if (t + 2 < nt) stage(sb, (t + 2) << 6);
        compute(cb);
        cb = (cb == 2) ? 0 : cb + 1;
        sb = (sb == 2) ? 0 : sb + 1;
    }
    VM_WAIT_LG(0);
    __builtin_amdgcn_s_barrier();
    asm volatile("" ::: "memory");
    compute(cb);

#pragma unroll
    for (int in2 = 0; in2 < 4; in2++) {
        int gcol = colBlk + wc * 64 + in2 * 16 + m16;
        float bb = bias ? bias[gcol] : 0.f;
#pragma unroll
        for (int im = 0; im < 4; im++) {
            int growb = rowBlk + wr * 64 + im * 16 + quad * 4;
#pragma unroll
            for (int r = 0; r < 4; r++) {
                float vv = acc[im][in2][r] + bb;
                if (ACT == 1) vv = sigmoidf_(vv);
                if (ACT == 2) vv = fmaxf(vv, 0.f);
                if (ACT == 3 && gcol < 1024) vv *= 0.08838834764831845f;
                long grow = growb + r;
                if (RES) vv += res[grow * ldRes + gcol];
                if (OUTF32) ((float*)Out)[grow * ldOut + colOff + gcol] = vv;
                else        ((u16*)Out)[grow * ldOut + colOff + gcol] = f2bf(vv);
            }
        }
    }
}

// ---------------------------------------------------------------------------
// Flash attention v5: 8 waves x 16 q-rows, 512 threads, grid 512 (XCD
// swizzle unchanged).  LDS 80 KB (Ks 2x16K, Vt 2x16K, Pa 16K) -> 2 blk/CU
// -> 16 waves/CU (4/SIMD; v4 had 2/SIMD at 124 VGPR).  Per-wave state
// halved: qf[4], sacc[4], o[8].  Swizzle involutions preserved: all wave
// row-bases are multiples of 8, so row&7 semantics identical to v4.
// ---------------------------------------------------------------------------
__global__ __launch_bounds__(512, 4) void flash_attn(const u16* __restrict__ qkv,
        const u16* __restrict__ vt, u16* __restrict__ ctx) {
    constexpr int S = 2048, HD = 128, KT = 64, LD = 3072;
    __shared__ u16 Ks[2][KT * 128];   // [krow][chunk^swz] 16 KB each
    __shared__ u16 Vt[2][HD * 64];    // [dh][chunk^swz]  16 KB each
    __shared__ u16 Pa[128 * 64];      // [qrow][chunk^swz] 16 KB

    int bid = blockIdx.x;
    int bh = ((bid & 7) << 2) | ((bid >> 3) & 3);
    int qt = bid >> 5;
    int b = bh >> 3, h = bh & 7;
    int tid = threadIdx.x, wv = tid >> 6, lane = tid & 63;   // wv 0..7
    int m16 = lane & 15, quad = lane >> 4;
    long rowBase = (long)b * S;
    const u16* kptr = qkv + 1024 + h * HD;
    const u16* vptr = vt + (long)bh * HD * S;

    int kLR = lane >> 4, kCk = lane & 15;
    int vLR = lane >> 3, vCk = lane & 7;

    // 16 q-rows per wave: qrow0 + m16
    bf16x8 qf[4];
    int qrow0 = qt * 128 + wv * 16;
#pragma unroll
    for (int kc = 0; kc < 4; kc++)
        qf[kc] = *(const bf16x8*)(qkv + (rowBase + qrow0 + m16) * LD
                                      + h * HD + kc * 32 + quad * 8);

    floatx4 o[8];
#pragma unroll
    for (int dt = 0; dt < 8; dt++) o[dt] = (floatx4){0.f, 0.f, 0.f, 0.f};
    float lsum[4];
#pragma unroll
    for (int r = 0; r < 4; r++) lsum[r] = 0.f;

    auto stage = [&](int buf, int krow0) {
#pragma unroll
        for (int it = 0; it < 2; it++) {
            // K: 4 rows per wave-iteration (64 lanes x 16B = 4 x 128 elems)
            int grl = wv * 8 + it * 4 + kLR;
            int gc = (kCk & 8) | ((kCk ^ grl) & 7);
            const u16* gK = kptr + (rowBase + krow0 + grl) * LD + gc * 8;
            __builtin_amdgcn_global_load_lds((gas_t)gK,
                    (las_t)&Ks[buf][(wv * 8 + it * 4) * 128], 16, 0, 0);
            // V: 8 rows per wave-iteration (64 lanes x 16B = 8 x 64 elems)
            int gvl = wv * 16 + it * 8 + vLR;
            int gvc = vCk ^ (gvl & 7);
            const u16* gV = vptr + (long)gvl * S + krow0 + gvc * 8;
            __builtin_amdgcn_global_load_lds((gas_t)gV,
                    (las_t)&Vt[buf][(wv * 16 + it * 8) * 64], 16, 0, 0);
        }
    };

    stage(0, 0);
    for (int kt = 0; kt < S / KT; kt++) {
        int cur = kt & 1;
        __syncthreads();
        if (kt + 1 < S / KT) stage(cur ^ 1, (kt + 1) * KT);

        // QK^T: 16 MFMA
        floatx4 sacc[4];
#pragma unroll
        for (int nt = 0; nt < 4; nt++) sacc[nt] = (floatx4){0.f, 0.f, 0.f, 0.f};
#pragma unroll
        for (int nt = 0; nt < 4; nt++)
#pragma unroll
            for (int kc = 0; kc < 4; kc++) {
                int c = kc * 4 + quad;
                int csw = (c & 8) | ((c ^ m16) & 7);
                bf16x8 kf = *(const bf16x8*)&Ks[cur][(nt * 16 + m16) * 128 + csw * 8];
                sacc[nt] = mfma16(qf[kc], kf, sacc[nt]);
            }

        // softmax (no-max, deferred row-sum)
#pragma unroll
        for (int r = 0; r < 4; r++) {
            float ps = 0.f;
#pragma unroll
            for (int nt = 0; nt < 4; nt++) {
                float pp = __expf(sacc[nt][r]);
                sacc[nt][r] = pp;
                ps += pp;
            }
            lsum[r] += ps;
        }

        // P -> Pa (per-wave 16-row region, XOR swizzle by qr&7)
#pragma unroll
        for (int nt = 0; nt < 4; nt++)
#pragma unroll
            for (int r = 0; r < 4; r++) {
                int qr = quad * 4 + r;
                int c = nt * 2 + (m16 >> 3);
                Pa[(wv * 16 + qr) * 64 + ((c ^ (qr & 7)) * 8) + (m16 & 7)] =
                    f2bf(sacc[nt][r]);
            }

        // PV: 16 MFMA
        bf16x8 pf[2];
#pragma unroll
        for (int kc = 0; kc < 2; kc++) {
            int c = kc * 4 + quad;
            int csw = (c ^ m16) & 7;
            pf[kc] = *(const bf16x8*)&Pa[(wv * 16 + m16) * 64 + csw * 8];
        }
#pragma unroll
        for (int dt = 0; dt < 8; dt++)
#pragma unroll
            for (int kc = 0; kc < 2; kc++) {
                int c = kc * 4 + quad;
                int csw = (c ^ m16) & 7;
                bf16x8 vf = *(const bf16x8*)&Vt[cur][(dt * 16 + m16) * 64 + csw * 8];
                o[dt] = mfma16(pf[kc], vf, o[dt]);
            }
    }

    // epilogue: row-sum reduce within 16-lane groups, scale, store
    float linv[4];
#pragma unroll
    for (int r = 0; r < 4; r++) {
        float rs = lsum[r];
#pragma unroll
        for (int off = 1; off < 16; off <<= 1)
            rs += __shfl_xor(rs, off, 64);
        linv[r] = 1.f / rs;
    }
#pragma unroll
    for (int dt = 0; dt < 8; dt++)
#pragma unroll
        for (int r = 0; r < 4; r++) {
            float val = o[dt][r] * linv[r];
            long grow = qt * 128 + wv * 16 + quad * 4 + r;
            ctx[(rowBase + grow) * 1024 + h * HD + dt * 16 + m16] = f2bf(val);
        }
}

// ---------------------------------------------------------------------------
// Launch.  Workspace map (MB offsets, lifetimes serial on stream):
//   [  0, 32) conc (u16 8192x2048)
//   [ 32, 48) slot1: xn -> ctx -> xn2
//   [ 48, 64) xn1 -> vt (16 MB) -> ffn1h low half
//   [ 64,112) gate (64..80) -> qkv (48 MB) -> {ffn1h high [64,80), x2 [80,112)}
//   [112,118) wscr: transposed weights (max 6 MB, merged QKV)
//   [118,~120) bias3 + delta + Btb + h_all
// ---------------------------------------------------------------------------
extern "C" void kernel_launch(void* const* d_in, const int* in_sizes, int n_in,
                              void* d_out, int out_size, void* d_ws, size_t ws_size,
                              hipStream_t stream) {
    (void)in_sizes; (void)n_in; (void)out_size; (void)ws_size;
    const float* x      = (const float*)d_in[0];
    const float* ln_g   = (const float*)d_in[1];
    const float* ln_b   = (const float*)d_in[2];
    const float* Wdelta = (const float*)d_in[3];
    const float* bdelta = (const float*)d_in[4];
    const float* Win    = (const float*)d_in[5];
    const float* b_in   = (const float*)d_in[6];
    const float* Wgate  = (const float*)d_in[7];
    const float* bgate  = (const float*)d_in[8];
    const float* Amat   = (const float*)d_in[9];
    const float* Cmat   = (const float*)d_in[10];
    const float* ln1_g  = (const float*)d_in[11];
    const float* ln1_b  = (const float*)d_in[12];
    const float* Wq     = (const float*)d_in[13];
    const float* bq     = (const float*)d_in[14];
    const float* Wk     = (const float*)d_in[15];
    const float* bk     = (const float*)d_in[16];
    const float* Wv     = (const float*)d_in[17];
    const float* bv     = (const float*)d_in[18];
    const float* Wo     = (const float*)d_in[19];
    const float* bo     = (const float*)d_in[20];
    const float* ln2_g  = (const float*)d_in[21];
    const float* ln2_b  = (const float*)d_in[22];
    const float* W1     = (const float*)d_in[23];
    const float* b1     = (const float*)d_in[24];
    const float* W2     = (const float*)d_in[25];
    const float* b2     = (const float*)d_in[26];
    const float* Wf     = (const float*)d_in[27];
    const float* bfp    = (const float*)d_in[28];
    const float* lnf_g  = (const float*)d_in[29];
    const float* lnf_b  = (const float*)d_in[30];

    char* base = (char*)d_ws;
    const size_t MB = 1u << 20;
    u16*   conc  = (u16*)(base + 0 * MB);
    u16*   slot1 = (u16*)(base + 32 * MB);
    u16*   xn1   = (u16*)(base + 48 * MB);
    u16*   qkv   = (u16*)(base + 64 * MB);
    u16*   wscr  = (u16*)(base + 112 * MB);
    float* bias3 = (float*)(base + 118 * MB);
    float* delta = (float*)(base + 118 * MB + 512 * 1024);
    float* Btb   = (float*)(base + 119 * MB);
    float* h_all = (float*)(base + 119 * MB + 512 * 1024);

    u16* xn    = slot1;
    u16* gate  = qkv;                        // dead before qkv written
    u16* ctx   = slot1;
    u16* xn2   = slot1;
    u16* vt    = xn1;                        // 16 MB, after xn1 consumed
    u16* ffn1h = xn1;                        // 32 MB: [48,80)
    float* x2  = (float*)(base + 80 * MB);   // 32 MB f32: [80,112)

    // 1) dual LN
    ln_dual_kernel<<<8192, 256, 0, stream>>>(x, ln_g, ln_b, ln1_g, ln1_b, xn, xn1);

    // 2) mamba projections (MFMA) + chunk-parallel scan
    delta_bt_kernel<<<128, 256, 0, stream>>>(xn, Wdelta, bdelta, Win, b_in, delta, Btb);
    scan_kernel<<<16, 256, 0, stream>>>(delta, Btb, Amat, h_all);

    // 3) gate = sigmoid(xn @ Wgate + bgate)   (256 WGs)
    transpose_cast<<<dim3(32, 32), 256, 0, stream>>>(Wgate, wscr, 1024, 1024, 0, 0);
    gemm_bt<1, 0, 0><<<dim3(8, 32), 512, 0, stream>>>(xn, wscr, bgate, nullptr,
            gate, 8192, 1024, 1024, 0, 1024, 0);
    // 4) mamba_out -> concat[:, :1024]
    mamba_out_kernel<<<8192, 256, 0, stream>>>(h_all, Cmat, gate, x, conc);

    // 5) merged QKV (Q cols pre-scaled by 1/sqrt(128) in epilogue, ACT=3) (768 WGs)
    transpose_cast<<<dim3(32, 32), 256, 0, stream>>>(Wq, wscr, 1024, 1024, 0, 0);
    transpose_cast<<<dim3(32, 32), 256, 0, stream>>>(Wk, wscr + 1024 * 1024, 1024, 1024, 0, 0);
    transpose_cast<<<dim3(32, 32), 256, 0, stream>>>(Wv, wscr + 2 * 1024 * 1024, 1024, 1024, 0, 0);
    concat_bias<<<12, 256, 0, stream>>>(bq, bk, bv, bias3);
    gemm_bt<3, 0, 0><<<dim3(24, 32), 512, 0, stream>>>(xn1, wscr, bias3, nullptr,
            qkv, 8192, 3072, 1024, 0, 3072, 0);

    // 5b) V -> vt[bh][dh][S] (xn1 dead after QKV GEMM)
    transpose_v<<<dim3(32, 2, 32), 256, 0, stream>>>(qkv, vt);

    // 6) attention (ctx overwrites xn in slot1)
    flash_attn<<<512, 512, 0, stream>>>(qkv, vt, ctx);

    // 7) x2 = x + ctx @ Wo + bo (f32; overwrites dead parts of qkv)
    transpose_cast<<<dim3(32, 32), 256, 0, stream>>>(Wo, wscr, 1024, 1024, 0, 0);
    gemm_bt<0, 1, 1><<<dim3(8, 32), 512, 0, stream>>>(ctx, wscr, bo, x,
            x2, 8192, 1024, 1024, 1024, 1024, 0);

    // 8) xn2 = LN(x2) -> bf16 (overwrites ctx)
    ln_one_kernel<1><<<8192, 256, 0, stream>>>(x2, ln2_g, ln2_b, xn2);

    // 9) FFN in two N-halves (ffn1h 32 MB reused)   (512 / 256 WGs)
    transpose_cast<<<dim3(64, 32), 256, 0, stream>>>(W1, wscr, 1024, 4096, 0, 0);
    gemm_bt<2, 0, 0><<<dim3(16, 32), 512, 0, stream>>>(xn2, wscr, b1, nullptr,
            ffn1h, 8192, 2048, 1024, 0, 2048, 0);
    transpose_cast<<<dim3(32, 64), 256, 0, stream>>>(W2, wscr, 2048, 1024, 0, 0);
    gemm_bt<0, 1, 1><<<dim3(8, 32), 512, 0, stream>>>(ffn1h, wscr, b2, x2,
            x2, 8192, 1024, 2048, 1024, 1024, 0);
    transpose_cast<<<dim3(64, 32), 256, 0, stream>>>(W1, wscr, 1024, 4096, 0, 2048);
    gemm_bt<2, 0, 0><<<dim3(16, 32), 512, 0, stream>>>(xn2, wscr, b1 + 2048, nullptr,
            ffn1h, 8192, 2048, 1024, 0, 2048, 0);
    transpose_cast<<<dim3(32, 64), 256, 0, stream>>>(W2, wscr, 2048, 1024, 2048, 0);
    gemm_bt<0, 1, 0><<<dim3(8, 32), 512, 0, stream>>>(ffn1h, wscr, nullptr, x2,
            conc, 8192, 1024, 2048, 1024, 2048, 1024);

    // 10) fused_pre = concat @ Wf + bf  (K=2048, f32 into d_out)
    transpose_cast<<<dim3(32, 64), 256, 0, stream>>>(Wf, wscr, 2048, 1024, 0, 0);
    gemm_bt<0, 0, 1><<<dim3(8, 32), 512, 0, stream>>>(conc, wscr, bfp, nullptr,
            (float*)d_out, 8192, 1024, 2048, 0, 1024, 0);

    // 11) final LN in place on d_out (f32)
    ln_one_kernel<0><<<8192, 256, 0, stream>>>((const float*)d_out, lnf_g, lnf_b, d_out);
}

// Round 9
// 741.354 us; speedup vs baseline: 1.0158x; 1.0097x over previous
//
#include <hip/hip_runtime.h>
#include <stdint.h>

// ---------------------------------------------------------------------------
// MambaFormer forward, MI355X/gfx950.  bf16 MFMA (16x16x32) for all GEMMs,
// fp32 accumulation & fp32 LayerNorms.  B=4 S=2048 D=1024 Ds=16 DFF=4096 H=8.
// R11 (resubmit x2): flash_attn v6 -- v4's mt=2 structure (fragment reuse
//     restored; v5's 1-tile/wave doubled LDS reads and regressed) +
//     counted-vmcnt double barrier (no vmcnt(0) drain per K-tile; the
//     gemm_bt v3b protocol) + setprio around MFMA clusters.
//     gemm_bt v3b unchanged (verified R9).
// ---------------------------------------------------------------------------

typedef __bf16 bf16x8 __attribute__((ext_vector_type(8)));
typedef float  floatx4 __attribute__((ext_vector_type(4)));
typedef unsigned short u16;

typedef const __attribute__((address_space(1))) void* gas_t;
typedef __attribute__((address_space(3))) void* las_t;

#define DEV static __device__ __forceinline__

DEV u16 f2bf(float f) {
    unsigned int u;
    __builtin_memcpy(&u, &f, 4);
    u += 0x7fffu + ((u >> 16) & 1u);   // RNE
    return (u16)(u >> 16);
}
DEV float bf2f(u16 h) {
    unsigned int u = ((unsigned int)h) << 16;
    float f; __builtin_memcpy(&f, &u, 4);
    return f;
}
DEV floatx4 mfma16(bf16x8 a, bf16x8 b, floatx4 c) {
    return __builtin_amdgcn_mfma_f32_16x16x32_bf16(a, b, c, 0, 0, 0);
}
DEV float sigmoidf_(float x) { return 1.f / (1.f + __expf(-x)); }

// ---------------------------------------------------------------------------
// Weight transpose + cast: reads in[(rowOff+k)*ldIn + colOff+n] (f32),
// writes out[n*K + k] (bf16).  grid = (N/32, K/32), block = 256.
// ---------------------------------------------------------------------------
__global__ __launch_bounds__(256) void transpose_cast(const float* __restrict__ in,
                                                      u16* __restrict__ out,
                                                      int K, int ldIn,
                                                      int rowOff, int colOff) {
    __shared__ float tile[32][33];
    int bx = blockIdx.x * 32;  // n base
    int by = blockIdx.y * 32;  // k base
    int tx = threadIdx.x & 31, ty = threadIdx.x >> 5;  // ty 0..7
    for (int i = ty; i < 32; i += 8)
        tile[i][tx] = in[(long)(rowOff + by + i) * ldIn + colOff + bx + tx];
    __syncthreads();
    for (int i = ty; i < 32; i += 8)
        out[(long)(bx + i) * K + by + tx] = f2bf(tile[tx][i]);
}

__global__ __launch_bounds__(256) void concat_bias(const float* __restrict__ a,
        const float* __restrict__ b, const float* __restrict__ c,
        float* __restrict__ out) {
    int i = blockIdx.x * 256 + threadIdx.x;   // 0..3071
    float v = (i < 1024) ? a[i] : (i < 2048 ? b[i - 1024] : c[i - 2048]);
    out[i] = v;
}

// ---------------------------------------------------------------------------
// V transpose (bf16): qkv cols [2048..3071] (LD 3072) -> vt[b*8+h][dh=128][S].
// ---------------------------------------------------------------------------
__global__ __launch_bounds__(256) void transpose_v(const u16* __restrict__ qkv,
                                                   u16* __restrict__ vt) {
    __shared__ u16 tile[64][72];
    int s0 = blockIdx.x * 64;
    int d0 = blockIdx.y * 64;
    int bh = blockIdx.z;                 // b*8 + h
    int b = bh >> 3, h = bh & 7;
    int tx = threadIdx.x & 15, ty = threadIdx.x >> 4;   // 16 x 16
    long srcBase = ((long)b * 2048) * 3072 + 2048 + h * 128 + d0;
    for (int i = ty; i < 64; i += 16) {
        ushort4 v4 = *(const ushort4*)(qkv + srcBase + (long)(s0 + i) * 3072 + tx * 4);
        *(ushort4*)&tile[i][tx * 4] = v4;
    }
    __syncthreads();
    long dstBase = ((long)bh * 128 + d0) * 2048 + s0;
    for (int i = ty; i < 64; i += 16) {
        ushort4 o4;
        o4.x = tile[tx * 4 + 0][i];
        o4.y = tile[tx * 4 + 1][i];
        o4.z = tile[tx * 4 + 2][i];
        o4.w = tile[tx * 4 + 3][i];
        *(ushort4*)(vt + dstBase + (long)i * 2048 + tx * 4) = o4;
    }
}

// ---------------------------------------------------------------------------
// Block-wide sum over 1024 cols (256 thr, 4 f32/thr).
// ---------------------------------------------------------------------------
DEV float block_sum(float v, volatile float* red) {
    for (int off = 32; off; off >>= 1) v += __shfl_down(v, off, 64);
    int lane = threadIdx.x & 63, wv = threadIdx.x >> 6;
    if (lane == 0) red[wv] = v;
    __syncthreads();
    return red[0] + red[1] + red[2] + red[3];
}

// Dual LayerNorm of x (shared stats): xn (g0/b0) and xn1 (g1/b1), bf16 out.
__global__ __launch_bounds__(256) void ln_dual_kernel(const float* __restrict__ x,
        const float* __restrict__ g0, const float* __restrict__ b0,
        const float* __restrict__ g1, const float* __restrict__ b1,
        u16* __restrict__ out0, u16* __restrict__ out1) {
    __shared__ float red[8];
    long row = blockIdx.x;
    float4 vx = ((const float4*)(x + row * 1024))[threadIdx.x];
    float s = block_sum(vx.x + vx.y + vx.z + vx.w, red);
    float mean = s * (1.f / 1024.f);
    float dx0 = vx.x - mean, dx1 = vx.y - mean, dx2 = vx.z - mean, dx3 = vx.w - mean;
    float s2 = block_sum(dx0*dx0 + dx1*dx1 + dx2*dx2 + dx3*dx3, red + 4);
    float rs = rsqrtf(s2 * (1.f / 1024.f) + 1e-5f);
    float4 gg = ((const float4*)g0)[threadIdx.x];
    float4 bb = ((const float4*)b0)[threadIdx.x];
    ushort4 o;
    o.x = f2bf(dx0 * rs * gg.x + bb.x); o.y = f2bf(dx1 * rs * gg.y + bb.y);
    o.z = f2bf(dx2 * rs * gg.z + bb.z); o.w = f2bf(dx3 * rs * gg.w + bb.w);
    ((ushort4*)(out0 + row * 1024))[threadIdx.x] = o;
    gg = ((const float4*)g1)[threadIdx.x];
    bb = ((const float4*)b1)[threadIdx.x];
    o.x = f2bf(dx0 * rs * gg.x + bb.x); o.y = f2bf(dx1 * rs * gg.y + bb.y);
    o.z = f2bf(dx2 * rs * gg.z + bb.z); o.w = f2bf(dx3 * rs * gg.w + bb.w);
    ((ushort4*)(out1 + row * 1024))[threadIdx.x] = o;
}

// Single LayerNorm.  OUTBF=1 -> bf16 out, else f32 out (in-place safe).
template <int OUTBF>
__global__ __launch_bounds__(256) void ln_one_kernel(const float* __restrict__ x,
        const float* __restrict__ g, const float* __restrict__ b,
        void* __restrict__ out) {
    __shared__ float red[8];
    long row = blockIdx.x;
    float4 vx = ((const float4*)(x + row * 1024))[threadIdx.x];
    float s = block_sum(vx.x + vx.y + vx.z + vx.w, red);
    float mean = s * (1.f / 1024.f);
    float dx0 = vx.x - mean, dx1 = vx.y - mean, dx2 = vx.z - mean, dx3 = vx.w - mean;
    float s2 = block_sum(dx0*dx0 + dx1*dx1 + dx2*dx2 + dx3*dx3, red + 4);
    float rs = rsqrtf(s2 * (1.f / 1024.f) + 1e-5f);
    float4 gg = ((const float4*)g)[threadIdx.x];
    float4 bb = ((const float4*)b)[threadIdx.x];
    float r0 = dx0 * rs * gg.x + bb.x, r1 = dx1 * rs * gg.y + bb.y;
    float r2 = dx2 * rs * gg.z + bb.z, r3 = dx3 * rs * gg.w + bb.w;
    if (OUTBF) {
        ushort4 o; o.x = f2bf(r0); o.y = f2bf(r1); o.z = f2bf(r2); o.w = f2bf(r3);
        ((ushort4*)((u16*)out + row * 1024))[threadIdx.x] = o;
    } else {
        float4 o; o.x = r0; o.y = r1; o.z = r2; o.w = r3;
        ((float4*)((float*)out + row * 1024))[threadIdx.x] = o;
    }
}

// ---------------------------------------------------------------------------
// delta = sigmoid(xn @ Wdelta + bdelta), Bt = xn @ Win + b_in  via MFMA.
// ---------------------------------------------------------------------------
__global__ __launch_bounds__(256) void delta_bt_kernel(const u16* __restrict__ xn,
        const float* __restrict__ Wd, const float* __restrict__ bd,
        const float* __restrict__ Wi, const float* __restrict__ bi,
        float* __restrict__ delta, float* __restrict__ Bt) {
    __shared__ u16 Wlds[2 * 32 * 64 * 8];   // 64 KB
    int tid = threadIdx.x;
    int wv = tid >> 6, lane = tid & 63;
    int m16 = lane & 15, quad = lane >> 4;

    for (int it = tid; it < 4096; it += 256) {
        int mat = it >> 11, rem = it & 2047;
        int c = rem >> 6, ln = rem & 63;
        int n = ln & 15, q = ln >> 4;
        const float* Wsrc = mat ? Wi : Wd;
        u16 tmp[8];
#pragma unroll
        for (int jj = 0; jj < 8; jj++)
            tmp[jj] = f2bf(Wsrc[(c * 32 + q * 8 + jj) * 16 + n]);
        *(int4*)&Wlds[(long)it * 8] = *(int4*)tmp;
    }
    __syncthreads();

    int row0 = blockIdx.x * 64 + wv * 16;
    floatx4 accD = (floatx4){0.f, 0.f, 0.f, 0.f};
    floatx4 accB = (floatx4){0.f, 0.f, 0.f, 0.f};
#pragma unroll 4
    for (int c = 0; c < 32; c++) {
        bf16x8 afrag = *(const bf16x8*)(xn + (long)(row0 + m16) * 1024 + c * 32 + quad * 8);
        bf16x8 bdv = *(const bf16x8*)&Wlds[(long)(c * 64 + lane) * 8];
        bf16x8 biv = *(const bf16x8*)&Wlds[(long)(2048 + c * 64 + lane) * 8];
        accD = mfma16(afrag, bdv, accD);
        accB = mfma16(afrag, biv, accB);
    }
    float bdd = bd[m16], bii = bi[m16];
#pragma unroll
    for (int r = 0; r < 4; r++) {
        long row = row0 + quad * 4 + r;
        delta[row * 16 + m16] = sigmoidf_(accD[r] + bdd);
        Bt[row * 16 + m16]    = accB[r] + bii;
    }
}

// ---------------------------------------------------------------------------
// Chunk-parallel scan v3: h_t = tanh((h_{t-1}*d_t) @ A + B_t).
// ---------------------------------------------------------------------------
__global__ __launch_bounds__(256) void scan_kernel(const float* __restrict__ delta,
        const float* __restrict__ Bt, const float* __restrict__ A,
        float* __restrict__ h_all) {
    int tid = threadIdx.x;
    int lane = tid & 63, wv = tid >> 6;
    int slotLocal = (wv << 2) + (lane >> 4);
    int s = blockIdx.x * 16 + slotLocal;     // 0..255
    int j = lane & 15;
    int b = s >> 6, chunk = s & 63;
    int t0 = chunk * 32;
    int srcBase = lane & 48;

    float Acol[16];
#pragma unroll
    for (int i = 0; i < 16; i++) Acol[i] = A[i * 16 + j];
    long base = (long)b * 2048 * 16 + j;

    const int W = 16, T = W + 32;            // 48 steps, 12 groups of 4
    float h = 0.f;
    float dbuf[2][4], bbuf[2][4];
#pragma unroll
    for (int u = 0; u < 4; u++) {
        int t = t0 - W + u; if (t < 0) t = 0;
        dbuf[0][u] = delta[base + (long)t * 16];
        bbuf[0][u] = Bt[base + (long)t * 16];
    }
    for (int g = 0; g < T / 4; g++) {
        int cb = g & 1, nb = cb ^ 1;
        if (g + 1 < T / 4) {
#pragma unroll
            for (int u = 0; u < 4; u++) {
                int t = t0 - W + (g + 1) * 4 + u; if (t < 0) t = 0;
                dbuf[nb][u] = delta[base + (long)t * 16];
                bbuf[nb][u] = Bt[base + (long)t * 16];
            }
        }
#pragma unroll
        for (int u = 0; u < 4; u++) {
            int t = t0 - W + g * 4 + u;
            float d = dbuf[cb][u], bt = bbuf[cb][u];
            float gg = h * d;
            float gv[16];
#pragma unroll
            for (int i = 0; i < 16; i++)
                gv[i] = __shfl(gg, srcBase + i, 64);
            float a0 = gv[0] * Acol[0], a1 = gv[1] * Acol[1];
            float a2 = gv[2] * Acol[2], a3 = gv[3] * Acol[3];
#pragma unroll
            for (int i = 4; i < 16; i += 4) {
                a0 += gv[i + 0] * Acol[i + 0];
                a1 += gv[i + 1] * Acol[i + 1];
                a2 += gv[i + 2] * Acol[i + 2];
                a3 += gv[i + 3] * Acol[i + 3];
            }
            float xx = (a0 + a1) + (a2 + a3) + bt;
            xx = fminf(fmaxf(xx, -15.f), 15.f);
            float e = __expf(2.f * xx);
            float hn = (e - 1.f) / (e + 1.f);
            if (t >= 0) h = hn;
            if (t >= t0) h_all[base + (long)t * 16] = h;
        }
    }
}

// ---------------------------------------------------------------------------
// mamba_out = (h_all @ C) * gate + x   -> bf16 into concat[:, 0:1024]
// ---------------------------------------------------------------------------
__global__ __launch_bounds__(256) void mamba_out_kernel(const float* __restrict__ h_all,
        const float* __restrict__ C, const u16* __restrict__ gate,
        const float* __restrict__ x, u16* __restrict__ concat) {
    __shared__ float hs[16];
    long row = blockIdx.x;
    if (threadIdx.x < 16) hs[threadIdx.x] = h_all[row * 16 + threadIdx.x];
    __syncthreads();
    int n = threadIdx.x * 4;
    float a0 = 0.f, a1 = 0.f, a2 = 0.f, a3 = 0.f;
#pragma unroll
    for (int i = 0; i < 16; i++) {
        float hv = hs[i];
        float4 cv = *(const float4*)(C + i * 1024 + n);
        a0 += hv * cv.x; a1 += hv * cv.y; a2 += hv * cv.z; a3 += hv * cv.w;
    }
    ushort4 gv = *(const ushort4*)(gate + row * 1024 + n);
    float4 xv  = *(const float4*)(x + row * 1024 + n);
    ushort4 o;
    o.x = f2bf(a0 * bf2f(gv.x) + xv.x);
    o.y = f2bf(a1 * bf2f(gv.y) + xv.y);
    o.z = f2bf(a2 * bf2f(gv.z) + xv.z);
    o.w = f2bf(a3 * bf2f(gv.w) + xv.w);
    *(ushort4*)(concat + row * 2048 + n) = o;
}

// ---------------------------------------------------------------------------
// Workhorse GEMM v3b (verified R9):  Out = epi(A[MxK] @ B^T[NxK]^T + bias).
// 256x128 tile, 512 thr / 8 waves, ring-3 LDS, BK=64, counted
// s_waitcnt vmcnt(6) lgkmcnt(0) + raw s_barrier, XOR-swizzled LDS,
// setprio, XCD-chunked bid swizzle.  UNCHANGED from the 753 us run.
// ---------------------------------------------------------------------------
#define VM_WAIT_LG(N) asm volatile("s_waitcnt vmcnt(" #N ") lgkmcnt(0)" ::: "memory")

template <int ACT, int RES, int OUTF32>
__global__ __launch_bounds__(512, 2) void gemm_bt(const u16* __restrict__ A,
        const u16* __restrict__ B, const float* __restrict__ bias,
        const float* __restrict__ res, void* __restrict__ Out,
        int M, int N, int K, int ldRes, int ldOut, int colOff) {
    __shared__ __align__(16) u16 smem[3 * 24576];   // 3 x 48 KB
    int tid = threadIdx.x;
    int wv = tid >> 6, lane = tid & 63;
    int wr = wv >> 1, wc = wv & 1;
    int m16 = lane & 15, quad = lane >> 4;
    int swz = m16 & 7;

    int nwg = gridDim.x * gridDim.y;
    int bid = blockIdx.y * gridDim.x + blockIdx.x;
    int sw = (bid & 7) * (nwg >> 3) + (bid >> 3);
    int bx = sw % gridDim.x, by = sw / gridDim.x;
    int rowBlk = by * 256, colBlk = bx * 128;

    int trow = tid >> 3;                         // row within a 64-row round
    int schk = ((tid & 7) ^ (trow & 7)) * 8;     // pre-swizzled k-chunk (elems)

    floatx4 acc[4][4];
#pragma unroll
    for (int i = 0; i < 4; i++)
#pragma unroll
        for (int j = 0; j < 4; j++) acc[i][j] = (floatx4){0.f, 0.f, 0.f, 0.f};

    auto stage = [&](int buf, int k0) {
        char* ab = (char*)smem + buf * 49152;
        const u16* gA = A + (long)(rowBlk + trow) * K + k0 + schk;
#pragma unroll
        for (int r = 0; r < 4; r++)
            __builtin_amdgcn_global_load_lds((gas_t)(gA + (long)(r * 64) * K),
                    (las_t)(ab + r * 8192 + wv * 1024), 16, 0, 0);
        const u16* gB = B + (long)(colBlk + trow) * K + k0 + schk;
#pragma unroll
        for (int r = 0; r < 2; r++)
            __builtin_amdgcn_global_load_lds((gas_t)(gB + (long)(r * 64) * K),
                    (las_t)(ab + 32768 + r * 8192 + wv * 1024), 16, 0, 0);
    };

    auto compute = [&](int buf) {
        const u16* Ab = smem + buf * 24576;      // [256][64] (chunk-swizzled)
        const u16* Bb = Ab + 16384;              // [128][64]
#pragma unroll
        for (int kk = 0; kk < 2; kk++) {
            int cs = ((kk * 4 + quad) ^ swz) * 8;
            bf16x8 af[4], bfv[4];
#pragma unroll
            for (int i = 0; i < 4; i++)
                af[i] = *(const bf16x8*)(Ab + (wr * 64 + i * 16 + m16) * 64 + cs);
#pragma unroll
            for (int i = 0; i < 4; i++)
                bfv[i] = *(const bf16x8*)(Bb + (wc * 64 + i * 16 + m16) * 64 + cs);
            __builtin_amdgcn_s_setprio(1);
#pragma unroll
            for (int im = 0; im < 4; im++)
#pragma unroll
                for (int in2 = 0; in2 < 4; in2++)
                    acc[im][in2] = mfma16(af[im], bfv[in2], acc[im][in2]);
            __builtin_amdgcn_s_setprio(0);
        }
    };

    stage(0, 0);
    stage(1, 64);
    int nt = K >> 6;
    int cb = 0, sb = 2;
    for (int t = 0; t < nt - 1; t++) {
        VM_WAIT_LG(6);                   // tile t landed; tile t+1 may fly;
        __builtin_amdgcn_s_barrier();    // no LDS reads in flight past here
        asm volatile("" ::: "memory");
        if (t + 2 < nt) stage(sb, (t + 2) << 6);
        compute(cb);
        cb = (cb == 2) ? 0 : cb + 1;
        sb = (sb == 2) ? 0 : sb + 1;
    }
    VM_WAIT_LG(0);
    __builtin_amdgcn_s_barrier();
    asm volatile("" ::: "memory");
    compute(cb);

#pragma unroll
    for (int in2 = 0; in2 < 4; in2++) {
        int gcol = colBlk + wc * 64 + in2 * 16 + m16;
        float bb = bias ? bias[gcol] : 0.f;
#pragma unroll
        for (int im = 0; im < 4; im++) {
            int growb = rowBlk + wr * 64 + im * 16 + quad * 4;
#pragma unroll
            for (int r = 0; r < 4; r++) {
                float vv = acc[im][in2][r] + bb;
                if (ACT == 1) vv = sigmoidf_(vv);
                if (ACT == 2) vv = fmaxf(vv, 0.f);
                if (ACT == 3 && gcol < 1024) vv *= 0.08838834764831845f;
                long grow = growb + r;
                if (RES) vv += res[grow * ldRes + gcol];
                if (OUTF32) ((float*)Out)[grow * ldOut + colOff + gcol] = vv;
                else        ((u16*)Out)[grow * ldOut + colOff + gcol] = f2bf(vv);
            }
        }
    }
}

// ---------------------------------------------------------------------------
// Flash attention v6: v4 body (4 waves x 32 q-rows, mt=2 fragment reuse,
// 80 KB LDS, 2 blk/CU) with the counted-vmcnt double-barrier protocol:
//   lgkm(0); barrier#1           (all waves done reading buf^1)
//   stage(t+1) -> buf^1          (WAR-safe: after barrier#1)
//   vmcnt(8) lgkm(0)             (tile t landed; t+1's 8 stay in flight)
//   barrier#2                    (collective: tile t resident)
//   compute(t)                   (setprio(1) around MFMA clusters)
// No vmcnt(0) drain in the main loop (the gemm_bt v3b lever, T4+T5).
// ---------------------------------------------------------------------------
__global__ __launch_bounds__(256, 2) void flash_attn(const u16* __restrict__ qkv,
        const u16* __restrict__ vt, u16* __restrict__ ctx) {
    constexpr int S = 2048, HD = 128, KT = 64, LD = 3072;
    __shared__ u16 Ks[2][KT * 128];   // [krow][chunk^swz] 16 KB each
    __shared__ u16 Vt[2][HD * 64];    // [dh][chunk^swz]  16 KB each
    __shared__ u16 Pa[128 * 64];      // [qrow][chunk^swz] 16 KB

    int bid = blockIdx.x;
    int bh = ((bid & 7) << 2) | ((bid >> 3) & 3);
    int qt = bid >> 5;
    int b = bh >> 3, h = bh & 7;
    int tid = threadIdx.x, wv = tid >> 6, lane = tid & 63;
    int m16 = lane & 15, quad = lane >> 4;
    long rowBase = (long)b * S;
    const u16* kptr = qkv + 1024 + h * HD;
    const u16* vptr = vt + (long)bh * HD * S;

    int kLR = lane >> 4, kCk = lane & 15;
    int vLR = lane >> 3, vCk = lane & 7;

    bf16x8 qf[2][4];
    int qrow0 = qt * 128 + wv * 32;
#pragma unroll
    for (int mt = 0; mt < 2; mt++)
#pragma unroll
        for (int kc = 0; kc < 4; kc++)
            qf[mt][kc] = *(const bf16x8*)(qkv + (rowBase + qrow0 + mt * 16 + m16) * LD
                                            + h * HD + kc * 32 + quad * 8);

    floatx4 o[2][8];
#pragma unroll
    for (int mt = 0; mt < 2; mt++)
#pragma unroll
        for (int dt = 0; dt < 8; dt++) o[mt][dt] = (floatx4){0.f, 0.f, 0.f, 0.f};
    float lsum[2][4];
#pragma unroll
    for (int mt = 0; mt < 2; mt++)
#pragma unroll
        for (int r = 0; r < 4; r++) lsum[mt][r] = 0.f;

    auto stage = [&](int buf, int krow0) {   // 8 global_load_lds per wave
#pragma unroll
        for (int it = 0; it < 4; it++) {
            int grl = wv * 16 + it * 4 + kLR;
            int gc = (kCk & 8) | ((kCk ^ grl) & 7);
            const u16* gK = kptr + (rowBase + krow0 + grl) * LD + gc * 8;
            __builtin_amdgcn_global_load_lds((gas_t)gK,
                    (las_t)&Ks[buf][(wv * 16 + it * 4) * 128], 16, 0, 0);
            int gvl = wv * 32 + it * 8 + vLR;
            int gvc = vCk ^ (gvl & 7);
            const u16* gV = vptr + (long)gvl * S + krow0 + gvc * 8;
            __builtin_amdgcn_global_load_lds((gas_t)gV,
                    (las_t)&Vt[buf][(wv * 32 + it * 8) * 64], 16, 0, 0);
        }
    };

    stage(0, 0);
    for (int kt = 0; kt < S / KT; kt++) {
        int cur = kt & 1;
        // barrier #1: every wave's LDS reads of buf[cur^1] are retired
        asm volatile("s_waitcnt lgkmcnt(0)" ::: "memory");
        __builtin_amdgcn_s_barrier();
        asm volatile("" ::: "memory");
        if (kt + 1 < S / KT) {
            stage(cur ^ 1, (kt + 1) * KT);
            VM_WAIT_LG(8);               // tile kt landed; kt+1's 8 in flight
        } else {
            VM_WAIT_LG(0);
        }
        __builtin_amdgcn_s_barrier();    // collective: tile kt resident
        asm volatile("" ::: "memory");

        floatx4 sacc[2][4];
#pragma unroll
        for (int mt = 0; mt < 2; mt++)
#pragma unroll
            for (int nt = 0; nt < 4; nt++) sacc[mt][nt] = (floatx4){0.f, 0.f, 0.f, 0.f};
        __builtin_amdgcn_s_setprio(1);
#pragma unroll
        for (int nt = 0; nt < 4; nt++)
#pragma unroll
            for (int kc = 0; kc < 4; kc++) {
                int c = kc * 4 + quad;
                int csw = (c & 8) | ((c ^ m16) & 7);
                bf16x8 kf = *(const bf16x8*)&Ks[cur][(nt * 16 + m16) * 128 + csw * 8];
                sacc[0][nt] = mfma16(qf[0][kc], kf, sacc[0][nt]);
                sacc[1][nt] = mfma16(qf[1][kc], kf, sacc[1][nt]);
            }
        __builtin_amdgcn_s_setprio(0);

#pragma unroll
        for (int mt = 0; mt < 2; mt++)
#pragma unroll
            for (int r = 0; r < 4; r++) {
                float ps = 0.f;
#pragma unroll
                for (int nt = 0; nt < 4; nt++) {
                    float pp = __expf(sacc[mt][nt][r]);
                    sacc[mt][nt][r] = pp;
                    ps += pp;
                }
                lsum[mt][r] += ps;
            }

#pragma unroll
        for (int mt = 0; mt < 2; mt++)
#pragma unroll
            for (int nt = 0; nt < 4; nt++)
#pragma unroll
                for (int r = 0; r < 4; r++) {
                    int qr = quad * 4 + r;
                    int c = nt * 2 + (m16 >> 3);
                    Pa[(wv * 32 + mt * 16 + qr) * 64 + ((c ^ (qr & 7)) * 8) + (m16 & 7)] =
                        f2bf(sacc[mt][nt][r]);
                }

        bf16x8 pf[2][2];
#pragma unroll
        for (int mt = 0; mt < 2; mt++)
#pragma unroll
            for (int kc = 0; kc < 2; kc++) {
                int c = kc * 4 + quad;
                int csw = (c ^ m16) & 7;
                pf[mt][kc] = *(const bf16x8*)&Pa[(wv * 32 + mt * 16 + m16) * 64 + csw * 8];
            }
        __builtin_amdgcn_s_setprio(1);
#pragma unroll
        for (int dt = 0; dt < 8; dt++)
#pragma unroll
            for (int kc = 0; kc < 2; kc++) {
                int c = kc * 4 + quad;
                int csw = (c ^ m16) & 7;
                bf16x8 vf = *(const bf16x8*)&Vt[cur][(dt * 16 + m16) * 64 + csw * 8];
                o[0][dt] = mfma16(pf[0][kc], vf, o[0][dt]);
                o[1][dt] = mfma16(pf[1][kc], vf, o[1][dt]);
            }
        __builtin_amdgcn_s_setprio(0);
    }

#pragma unroll
    for (int mt = 0; mt < 2; mt++) {
        float linv[4];
#pragma unroll
        for (int r = 0; r < 4; r++) {
            float rs = lsum[mt][r];
#pragma unroll
            for (int off = 1; off < 16; off <<= 1)
                rs += __shfl_xor(rs, off, 64);
            linv[r] = 1.f / rs;
        }
#pragma unroll
        for (int dt = 0; dt < 8; dt++)
#pragma unroll
            for (int r = 0; r < 4; r++) {
                float val = o[mt][dt][r] * linv[r];
                long grow = qt * 128 + wv * 32 + mt * 16 + quad * 4 + r;
                ctx[(rowBase + grow) * 1024 + h * HD + dt * 16 + m16] = f2bf(val);
            }
    }
}

// ---------------------------------------------------------------------------
// Launch.  Workspace map (MB offsets, lifetimes serial on stream):
//   [  0, 32) conc (u16 8192x2048)
//   [ 32, 48) slot1: xn -> ctx -> xn2
//   [ 48, 64) xn1 -> vt (16 MB) -> ffn1h low half
//   [ 64,112) gate (64..80) -> qkv (48 MB) -> {ffn1h high [64,80), x2 [80,112)}
//   [112,118) wscr: transposed weights (max 6 MB, merged QKV)
//   [118,~120) bias3 + delta + Btb + h_all
// ---------------------------------------------------------------------------
extern "C" void kernel_launch(void* const* d_in, const int* in_sizes, int n_in,
                              void* d_out, int out_size, void* d_ws, size_t ws_size,
                              hipStream_t stream) {
    (void)in_sizes; (void)n_in; (void)out_size; (void)ws_size;
    const float* x      = (const float*)d_in[0];
    const float* ln_g   = (const float*)d_in[1];
    const float* ln_b   = (const float*)d_in[2];
    const float* Wdelta = (const float*)d_in[3];
    const float* bdelta = (const float*)d_in[4];
    const float* Win    = (const float*)d_in[5];
    const float* b_in   = (const float*)d_in[6];
    const float* Wgate  = (const float*)d_in[7];
    const float* bgate  = (const float*)d_in[8];
    const float* Amat   = (const float*)d_in[9];
    const float* Cmat   = (const float*)d_in[10];
    const float* ln1_g  = (const float*)d_in[11];
    const float* ln1_b  = (const float*)d_in[12];
    const float* Wq     = (const float*)d_in[13];
    const float* bq     = (const float*)d_in[14];
    const float* Wk     = (const float*)d_in[15];
    const float* bk     = (const float*)d_in[16];
    const float* Wv     = (const float*)d_in[17];
    const float* bv     = (const float*)d_in[18];
    const float* Wo     = (const float*)d_in[19];
    const float* bo     = (const float*)d_in[20];
    const float* ln2_g  = (const float*)d_in[21];
    const float* ln2_b  = (const float*)d_in[22];
    const float* W1     = (const float*)d_in[23];
    const float* b1     = (const float*)d_in[24];
    const float* W2     = (const float*)d_in[25];
    const float* b2     = (const float*)d_in[26];
    const float* Wf     = (const float*)d_in[27];
    const float* bfp    = (const float*)d_in[28];
    const float* lnf_g  = (const float*)d_in[29];
    const float* lnf_b  = (const float*)d_in[30];

    char* base = (char*)d_ws;
    const size_t MB = 1u << 20;
    u16*   conc  = (u16*)(base + 0 * MB);
    u16*   slot1 = (u16*)(base + 32 * MB);
    u16*   xn1   = (u16*)(base + 48 * MB);
    u16*   qkv   = (u16*)(base + 64 * MB);
    u16*   wscr  = (u16*)(base + 112 * MB);
    float* bias3 = (float*)(base + 118 * MB);
    float* delta = (float*)(base + 118 * MB + 512 * 1024);
    float* Btb   = (float*)(base + 119 * MB);
    float* h_all = (float*)(base + 119 * MB + 512 * 1024);

    u16* xn    = slot1;
    u16* gate  = qkv;                        // dead before qkv written
    u16* ctx   = slot1;
    u16* xn2   = slot1;
    u16* vt    = xn1;                        // 16 MB, after xn1 consumed
    u16* ffn1h = xn1;                        // 32 MB: [48,80)
    float* x2  = (float*)(base + 80 * MB);   // 32 MB f32: [80,112)

    // 1) dual LN
    ln_dual_kernel<<<8192, 256, 0, stream>>>(x, ln_g, ln_b, ln1_g, ln1_b, xn, xn1);

    // 2) mamba projections (MFMA) + chunk-parallel scan
    delta_bt_kernel<<<128, 256, 0, stream>>>(xn, Wdelta, bdelta, Win, b_in, delta, Btb);
    scan_kernel<<<16, 256, 0, stream>>>(delta, Btb, Amat, h_all);

    // 3) gate = sigmoid(xn @ Wgate + bgate)   (256 WGs)
    transpose_cast<<<dim3(32, 32), 256, 0, stream>>>(Wgate, wscr, 1024, 1024, 0, 0);
    gemm_bt<1, 0, 0><<<dim3(8, 32), 512, 0, stream>>>(xn, wscr, bgate, nullptr,
            gate, 8192, 1024, 1024, 0, 1024, 0);
    // 4) mamba_out -> concat[:, :1024]
    mamba_out_kernel<<<8192, 256, 0, stream>>>(h_all, Cmat, gate, x, conc);

    // 5) merged QKV (Q cols pre-scaled by 1/sqrt(128) in epilogue, ACT=3) (768 WGs)
    transpose_cast<<<dim3(32, 32), 256, 0, stream>>>(Wq, wscr, 1024, 1024, 0, 0);
    transpose_cast<<<dim3(32, 32), 256, 0, stream>>>(Wk, wscr + 1024 * 1024, 1024, 1024, 0, 0);
    transpose_cast<<<dim3(32, 32), 256, 0, stream>>>(Wv, wscr + 2 * 1024 * 1024, 1024, 1024, 0, 0);
    concat_bias<<<12, 256, 0, stream>>>(bq, bk, bv, bias3);
    gemm_bt<3, 0, 0><<<dim3(24, 32), 512, 0, stream>>>(xn1, wscr, bias3, nullptr,
            qkv, 8192, 3072, 1024, 0, 3072, 0);

    // 5b) V -> vt[bh][dh][S] (xn1 dead after QKV GEMM)
    transpose_v<<<dim3(32, 2, 32), 256, 0, stream>>>(qkv, vt);

    // 6) attention (ctx overwrites xn in slot1)
    flash_attn<<<512, 256, 0, stream>>>(qkv, vt, ctx);

    // 7) x2 = x + ctx @ Wo + bo (f32; overwrites dead parts of qkv)
    transpose_cast<<<dim3(32, 32), 256, 0, stream>>>(Wo, wscr, 1024, 1024, 0, 0);
    gemm_bt<0, 1, 1><<<dim3(8, 32), 512, 0, stream>>>(ctx, wscr, bo, x,
            x2, 8192, 1024, 1024, 1024, 1024, 0);

    // 8) xn2 = LN(x2) -> bf16 (overwrites ctx)
    ln_one_kernel<1><<<8192, 256, 0, stream>>>(x2, ln2_g, ln2_b, xn2);

    // 9) FFN in two N-halves (ffn1h 32 MB reused)   (512 / 256 WGs)
    transpose_cast<<<dim3(64, 32), 256, 0, stream>>>(W1, wscr, 1024, 4096, 0, 0);
    gemm_bt<2, 0, 0><<<dim3(16, 32), 512, 0, stream>>>(xn2, wscr, b1, nullptr,
            ffn1h, 8192, 2048, 1024, 0, 2048, 0);
    transpose_cast<<<dim3(32, 64), 256, 0, stream>>>(W2, wscr, 2048, 1024, 0, 0);
    gemm_bt<0, 1, 1><<<dim3(8, 32), 512, 0, stream>>>(ffn1h, wscr, b2, x2,
            x2, 8192, 1024, 2048, 1024, 1024, 0);
    transpose_cast<<<dim3(64, 32), 256, 0, stream>>>(W1, wscr, 1024, 4096, 0, 2048);
    gemm_bt<2, 0, 0><<<dim3(16, 32), 512, 0, stream>>>(xn2, wscr, b1 + 2048, nullptr,
            ffn1h, 8192, 2048, 1024, 0, 2048, 0);
    transpose_cast<<<dim3(32, 64), 256, 0, stream>>>(W2, wscr, 2048, 1024, 2048, 0);
    gemm_bt<0, 1, 0><<<dim3(8, 32), 512, 0, stream>>>(ffn1h, wscr, nullptr, x2,
            conc, 8192, 1024, 2048, 1024, 2048, 1024);

    // 10) fused_pre = concat @ Wf + bf  (K=2048, f32 into d_out)
    transpose_cast<<<dim3(32, 64), 256, 0, stream>>>(Wf, wscr, 2048, 1024, 0, 0);
    gemm_bt<0, 0, 1><<<dim3(8, 32), 512, 0, stream>>>(conc, wscr, bfp, nullptr,
            (float*)d_out, 8192, 1024, 2048, 0, 1024, 0);

    // 11) final LN in place on d_out (f32)
    ln_one_kernel<0><<<8192, 256, 0, stream>>>((const float*)d_out, lnf_g, lnf_b, d_out);
}

// Round 10
// 735.441 us; speedup vs baseline: 1.0239x; 1.0080x over previous
//
#include <hip/hip_runtime.h>
#include <stdint.h>

// ---------------------------------------------------------------------------
// MambaFormer forward, MI355X/gfx950.  bf16 MFMA (16x16x32) for all GEMMs,
// fp32 accumulation & fp32 LayerNorms.  B=4 S=2048 D=1024 Ds=16 DFF=4096 H=8.
// R12: gemm_bt v4 -- BK 64->32, ring-3 LDS 72 KB -> 2 blocks/CU (4 waves/
//     SIMD, was 1 blk/CU at 144 KB).  Same verified ring/counted-vmcnt/
//     swizzle structure (stage=3 loads -> vmcnt(3); mod-4 chunk XOR).
//     launch_bounds(512,4) to guarantee the 2-block occupancy.
//     flash_attn v6 unchanged (741.4 us run).
// ---------------------------------------------------------------------------

typedef __bf16 bf16x8 __attribute__((ext_vector_type(8)));
typedef float  floatx4 __attribute__((ext_vector_type(4)));
typedef unsigned short u16;

typedef const __attribute__((address_space(1))) void* gas_t;
typedef __attribute__((address_space(3))) void* las_t;

#define DEV static __device__ __forceinline__

DEV u16 f2bf(float f) {
    unsigned int u;
    __builtin_memcpy(&u, &f, 4);
    u += 0x7fffu + ((u >> 16) & 1u);   // RNE
    return (u16)(u >> 16);
}
DEV float bf2f(u16 h) {
    unsigned int u = ((unsigned int)h) << 16;
    float f; __builtin_memcpy(&f, &u, 4);
    return f;
}
DEV floatx4 mfma16(bf16x8 a, bf16x8 b, floatx4 c) {
    return __builtin_amdgcn_mfma_f32_16x16x32_bf16(a, b, c, 0, 0, 0);
}
DEV float sigmoidf_(float x) { return 1.f / (1.f + __expf(-x)); }

// ---------------------------------------------------------------------------
// Weight transpose + cast: reads in[(rowOff+k)*ldIn + colOff+n] (f32),
// writes out[n*K + k] (bf16).  grid = (N/32, K/32), block = 256.
// ---------------------------------------------------------------------------
__global__ __launch_bounds__(256) void transpose_cast(const float* __restrict__ in,
                                                      u16* __restrict__ out,
                                                      int K, int ldIn,
                                                      int rowOff, int colOff) {
    __shared__ float tile[32][33];
    int bx = blockIdx.x * 32;  // n base
    int by = blockIdx.y * 32;  // k base
    int tx = threadIdx.x & 31, ty = threadIdx.x >> 5;  // ty 0..7
    for (int i = ty; i < 32; i += 8)
        tile[i][tx] = in[(long)(rowOff + by + i) * ldIn + colOff + bx + tx];
    __syncthreads();
    for (int i = ty; i < 32; i += 8)
        out[(long)(bx + i) * K + by + tx] = f2bf(tile[tx][i]);
}

__global__ __launch_bounds__(256) void concat_bias(const float* __restrict__ a,
        const float* __restrict__ b, const float* __restrict__ c,
        float* __restrict__ out) {
    int i = blockIdx.x * 256 + threadIdx.x;   // 0..3071
    float v = (i < 1024) ? a[i] : (i < 2048 ? b[i - 1024] : c[i - 2048]);
    out[i] = v;
}

// ---------------------------------------------------------------------------
// V transpose (bf16): qkv cols [2048..3071] (LD 3072) -> vt[b*8+h][dh=128][S].
// ---------------------------------------------------------------------------
__global__ __launch_bounds__(256) void transpose_v(const u16* __restrict__ qkv,
                                                   u16* __restrict__ vt) {
    __shared__ u16 tile[64][72];
    int s0 = blockIdx.x * 64;
    int d0 = blockIdx.y * 64;
    int bh = blockIdx.z;                 // b*8 + h
    int b = bh >> 3, h = bh & 7;
    int tx = threadIdx.x & 15, ty = threadIdx.x >> 4;   // 16 x 16
    long srcBase = ((long)b * 2048) * 3072 + 2048 + h * 128 + d0;
    for (int i = ty; i < 64; i += 16) {
        ushort4 v4 = *(const ushort4*)(qkv + srcBase + (long)(s0 + i) * 3072 + tx * 4);
        *(ushort4*)&tile[i][tx * 4] = v4;
    }
    __syncthreads();
    long dstBase = ((long)bh * 128 + d0) * 2048 + s0;
    for (int i = ty; i < 64; i += 16) {
        ushort4 o4;
        o4.x = tile[tx * 4 + 0][i];
        o4.y = tile[tx * 4 + 1][i];
        o4.z = tile[tx * 4 + 2][i];
        o4.w = tile[tx * 4 + 3][i];
        *(ushort4*)(vt + dstBase + (long)i * 2048 + tx * 4) = o4;
    }
}

// ---------------------------------------------------------------------------
// Block-wide sum over 1024 cols (256 thr, 4 f32/thr).
// ---------------------------------------------------------------------------
DEV float block_sum(float v, volatile float* red) {
    for (int off = 32; off; off >>= 1) v += __shfl_down(v, off, 64);
    int lane = threadIdx.x & 63, wv = threadIdx.x >> 6;
    if (lane == 0) red[wv] = v;
    __syncthreads();
    return red[0] + red[1] + red[2] + red[3];
}

// Dual LayerNorm of x (shared stats): xn (g0/b0) and xn1 (g1/b1), bf16 out.
__global__ __launch_bounds__(256) void ln_dual_kernel(const float* __restrict__ x,
        const float* __restrict__ g0, const float* __restrict__ b0,
        const float* __restrict__ g1, const float* __restrict__ b1,
        u16* __restrict__ out0, u16* __restrict__ out1) {
    __shared__ float red[8];
    long row = blockIdx.x;
    float4 vx = ((const float4*)(x + row * 1024))[threadIdx.x];
    float s = block_sum(vx.x + vx.y + vx.z + vx.w, red);
    float mean = s * (1.f / 1024.f);
    float dx0 = vx.x - mean, dx1 = vx.y - mean, dx2 = vx.z - mean, dx3 = vx.w - mean;
    float s2 = block_sum(dx0*dx0 + dx1*dx1 + dx2*dx2 + dx3*dx3, red + 4);
    float rs = rsqrtf(s2 * (1.f / 1024.f) + 1e-5f);
    float4 gg = ((const float4*)g0)[threadIdx.x];
    float4 bb = ((const float4*)b0)[threadIdx.x];
    ushort4 o;
    o.x = f2bf(dx0 * rs * gg.x + bb.x); o.y = f2bf(dx1 * rs * gg.y + bb.y);
    o.z = f2bf(dx2 * rs * gg.z + bb.z); o.w = f2bf(dx3 * rs * gg.w + bb.w);
    ((ushort4*)(out0 + row * 1024))[threadIdx.x] = o;
    gg = ((const float4*)g1)[threadIdx.x];
    bb = ((const float4*)b1)[threadIdx.x];
    o.x = f2bf(dx0 * rs * gg.x + bb.x); o.y = f2bf(dx1 * rs * gg.y + bb.y);
    o.z = f2bf(dx2 * rs * gg.z + bb.z); o.w = f2bf(dx3 * rs * gg.w + bb.w);
    ((ushort4*)(out1 + row * 1024))[threadIdx.x] = o;
}

// Single LayerNorm.  OUTBF=1 -> bf16 out, else f32 out (in-place safe).
template <int OUTBF>
__global__ __launch_bounds__(256) void ln_one_kernel(const float* __restrict__ x,
        const float* __restrict__ g, const float* __restrict__ b,
        void* __restrict__ out) {
    __shared__ float red[8];
    long row = blockIdx.x;
    float4 vx = ((const float4*)(x + row * 1024))[threadIdx.x];
    float s = block_sum(vx.x + vx.y + vx.z + vx.w, red);
    float mean = s * (1.f / 1024.f);
    float dx0 = vx.x - mean, dx1 = vx.y - mean, dx2 = vx.z - mean, dx3 = vx.w - mean;
    float s2 = block_sum(dx0*dx0 + dx1*dx1 + dx2*dx2 + dx3*dx3, red + 4);
    float rs = rsqrtf(s2 * (1.f / 1024.f) + 1e-5f);
    float4 gg = ((const float4*)g)[threadIdx.x];
    float4 bb = ((const float4*)b)[threadIdx.x];
    float r0 = dx0 * rs * gg.x + bb.x, r1 = dx1 * rs * gg.y + bb.y;
    float r2 = dx2 * rs * gg.z + bb.z, r3 = dx3 * rs * gg.w + bb.w;
    if (OUTBF) {
        ushort4 o; o.x = f2bf(r0); o.y = f2bf(r1); o.z = f2bf(r2); o.w = f2bf(r3);
        ((ushort4*)((u16*)out + row * 1024))[threadIdx.x] = o;
    } else {
        float4 o; o.x = r0; o.y = r1; o.z = r2; o.w = r3;
        ((float4*)((float*)out + row * 1024))[threadIdx.x] = o;
    }
}

// ---------------------------------------------------------------------------
// delta = sigmoid(xn @ Wdelta + bdelta), Bt = xn @ Win + b_in  via MFMA.
// ---------------------------------------------------------------------------
__global__ __launch_bounds__(256) void delta_bt_kernel(const u16* __restrict__ xn,
        const float* __restrict__ Wd, const float* __restrict__ bd,
        const float* __restrict__ Wi, const float* __restrict__ bi,
        float* __restrict__ delta, float* __restrict__ Bt) {
    __shared__ u16 Wlds[2 * 32 * 64 * 8];   // 64 KB
    int tid = threadIdx.x;
    int wv = tid >> 6, lane = tid & 63;
    int m16 = lane & 15, quad = lane >> 4;

    for (int it = tid; it < 4096; it += 256) {
        int mat = it >> 11, rem = it & 2047;
        int c = rem >> 6, ln = rem & 63;
        int n = ln & 15, q = ln >> 4;
        const float* Wsrc = mat ? Wi : Wd;
        u16 tmp[8];
#pragma unroll
        for (int jj = 0; jj < 8; jj++)
            tmp[jj] = f2bf(Wsrc[(c * 32 + q * 8 + jj) * 16 + n]);
        *(int4*)&Wlds[(long)it * 8] = *(int4*)tmp;
    }
    __syncthreads();

    int row0 = blockIdx.x * 64 + wv * 16;
    floatx4 accD = (floatx4){0.f, 0.f, 0.f, 0.f};
    floatx4 accB = (floatx4){0.f, 0.f, 0.f, 0.f};
#pragma unroll 4
    for (int c = 0; c < 32; c++) {
        bf16x8 afrag = *(const bf16x8*)(xn + (long)(row0 + m16) * 1024 + c * 32 + quad * 8);
        bf16x8 bdv = *(const bf16x8*)&Wlds[(long)(c * 64 + lane) * 8];
        bf16x8 biv = *(const bf16x8*)&Wlds[(long)(2048 + c * 64 + lane) * 8];
        accD = mfma16(afrag, bdv, accD);
        accB = mfma16(afrag, biv, accB);
    }
    float bdd = bd[m16], bii = bi[m16];
#pragma unroll
    for (int r = 0; r < 4; r++) {
        long row = row0 + quad * 4 + r;
        delta[row * 16 + m16] = sigmoidf_(accD[r] + bdd);
        Bt[row * 16 + m16]    = accB[r] + bii;
    }
}

// ---------------------------------------------------------------------------
// Chunk-parallel scan v3: h_t = tanh((h_{t-1}*d_t) @ A + B_t).
// ---------------------------------------------------------------------------
__global__ __launch_bounds__(256) void scan_kernel(const float* __restrict__ delta,
        const float* __restrict__ Bt, const float* __restrict__ A,
        float* __restrict__ h_all) {
    int tid = threadIdx.x;
    int lane = tid & 63, wv = tid >> 6;
    int slotLocal = (wv << 2) + (lane >> 4);
    int s = blockIdx.x * 16 + slotLocal;     // 0..255
    int j = lane & 15;
    int b = s >> 6, chunk = s & 63;
    int t0 = chunk * 32;
    int srcBase = lane & 48;

    float Acol[16];
#pragma unroll
    for (int i = 0; i < 16; i++) Acol[i] = A[i * 16 + j];
    long base = (long)b * 2048 * 16 + j;

    const int W = 16, T = W + 32;            // 48 steps, 12 groups of 4
    float h = 0.f;
    float dbuf[2][4], bbuf[2][4];
#pragma unroll
    for (int u = 0; u < 4; u++) {
        int t = t0 - W + u; if (t < 0) t = 0;
        dbuf[0][u] = delta[base + (long)t * 16];
        bbuf[0][u] = Bt[base + (long)t * 16];
    }
    for (int g = 0; g < T / 4; g++) {
        int cb = g & 1, nb = cb ^ 1;
        if (g + 1 < T / 4) {
#pragma unroll
            for (int u = 0; u < 4; u++) {
                int t = t0 - W + (g + 1) * 4 + u; if (t < 0) t = 0;
                dbuf[nb][u] = delta[base + (long)t * 16];
                bbuf[nb][u] = Bt[base + (long)t * 16];
            }
        }
#pragma unroll
        for (int u = 0; u < 4; u++) {
            int t = t0 - W + g * 4 + u;
            float d = dbuf[cb][u], bt = bbuf[cb][u];
            float gg = h * d;
            float gv[16];
#pragma unroll
            for (int i = 0; i < 16; i++)
                gv[i] = __shfl(gg, srcBase + i, 64);
            float a0 = gv[0] * Acol[0], a1 = gv[1] * Acol[1];
            float a2 = gv[2] * Acol[2], a3 = gv[3] * Acol[3];
#pragma unroll
            for (int i = 4; i < 16; i += 4) {
                a0 += gv[i + 0] * Acol[i + 0];
                a1 += gv[i + 1] * Acol[i + 1];
                a2 += gv[i + 2] * Acol[i + 2];
                a3 += gv[i + 3] * Acol[i + 3];
            }
            float xx = (a0 + a1) + (a2 + a3) + bt;
            xx = fminf(fmaxf(xx, -15.f), 15.f);
            float e = __expf(2.f * xx);
            float hn = (e - 1.f) / (e + 1.f);
            if (t >= 0) h = hn;
            if (t >= t0) h_all[base + (long)t * 16] = h;
        }
    }
}

// ---------------------------------------------------------------------------
// mamba_out = (h_all @ C) * gate + x   -> bf16 into concat[:, 0:1024]
// ---------------------------------------------------------------------------
__global__ __launch_bounds__(256) void mamba_out_kernel(const float* __restrict__ h_all,
        const float* __restrict__ C, const u16* __restrict__ gate,
        const float* __restrict__ x, u16* __restrict__ concat) {
    __shared__ float hs[16];
    long row = blockIdx.x;
    if (threadIdx.x < 16) hs[threadIdx.x] = h_all[row * 16 + threadIdx.x];
    __syncthreads();
    int n = threadIdx.x * 4;
    float a0 = 0.f, a1 = 0.f, a2 = 0.f, a3 = 0.f;
#pragma unroll
    for (int i = 0; i < 16; i++) {
        float hv = hs[i];
        float4 cv = *(const float4*)(C + i * 1024 + n);
        a0 += hv * cv.x; a1 += hv * cv.y; a2 += hv * cv.z; a3 += hv * cv.w;
    }
    ushort4 gv = *(const ushort4*)(gate + row * 1024 + n);
    float4 xv  = *(const float4*)(x + row * 1024 + n);
    ushort4 o;
    o.x = f2bf(a0 * bf2f(gv.x) + xv.x);
    o.y = f2bf(a1 * bf2f(gv.y) + xv.y);
    o.z = f2bf(a2 * bf2f(gv.z) + xv.z);
    o.w = f2bf(a3 * bf2f(gv.w) + xv.w);
    *(ushort4*)(concat + row * 2048 + n) = o;
}

// ---------------------------------------------------------------------------
// Workhorse GEMM v4:  Out = epi(A[MxK] @ B^T[NxK]^T + bias[n]).
// 256x128 tile, 512 thr / 8 waves (4M x 2N), per-wave 64x64 out (acc[4][4]).
// BK=32.  Ring-3 LDS (3 x {A 16KB + B 8KB} = 72 KB -> 2 blocks/CU,
// 4 waves/SIMD).  Stage issued 2 tiles ahead; per-tile
// s_waitcnt vmcnt(3) lgkmcnt(0) + raw s_barrier (counted protocol, T4);
// stage = 3 global_load_lds/wave (2 A rounds + 1 B).
// LDS chunk-XOR swizzle (mod-4): write chunk (tid&3)^(trow&3) via
// pre-swizzled global src + linear dst; read slot quad^(m16&3) (same
// involution -- rule #21).  setprio (T5), XCD-chunked bid swizzle (T1).
// launch_bounds(512,4) caps VGPR at 128 to guarantee 2-block occupancy.
// ACT: 0 none, 1 sigmoid, 2 relu, 3 scale cols<1024 by 1/sqrt(128) (QKV).
// RES: +res[grow*ldRes+gcol] (f32).  OUTF32: f32 out else bf16.
// Requires: M%256==0, N%128==0, K%32==0, K>=96, (gridX*gridY)%8==0.
// ---------------------------------------------------------------------------
#define VM_WAIT_LG(N) asm volatile("s_waitcnt vmcnt(" #N ") lgkmcnt(0)" ::: "memory")

template <int ACT, int RES, int OUTF32>
__global__ __launch_bounds__(512, 4) void gemm_bt(const u16* __restrict__ A,
        const u16* __restrict__ B, const float* __restrict__ bias,
        const float* __restrict__ res, void* __restrict__ Out,
        int M, int N, int K, int ldRes, int ldOut, int colOff) {
    __shared__ __align__(16) u16 smem[3 * 12288];   // 3 x 24 KB = 72 KB
    int tid = threadIdx.x;
    int wv = tid >> 6, lane = tid & 63;
    int wr = wv >> 1, wc = wv & 1;
    int m16 = lane & 15, quad = lane >> 4;
    int swz = m16 & 3;

    int nwg = gridDim.x * gridDim.y;
    int bid = blockIdx.y * gridDim.x + blockIdx.x;
    int sw = (bid & 7) * (nwg >> 3) + (bid >> 3);
    int bx = sw % gridDim.x, by = sw / gridDim.x;
    int rowBlk = by * 256, colBlk = bx * 128;

    int trow = tid >> 2;                         // row within a 128-row round
    int schk = ((tid & 3) ^ (trow & 3)) * 8;     // pre-swizzled k-chunk (elems)

    floatx4 acc[4][4];
#pragma unroll
    for (int i = 0; i < 4; i++)
#pragma unroll
        for (int j = 0; j < 4; j++) acc[i][j] = (floatx4){0.f, 0.f, 0.f, 0.f};

    auto stage = [&](int buf, int k0) {          // 3 global_load_lds / wave
        char* ab = (char*)smem + buf * 24576;
        const u16* gA = A + (long)(rowBlk + trow) * K + k0 + schk;
#pragma unroll
        for (int r = 0; r < 2; r++)
            __builtin_amdgcn_global_load_lds((gas_t)(gA + (long)(r * 128) * K),
                    (las_t)(ab + r * 8192 + wv * 1024), 16, 0, 0);
        const u16* gB = B + (long)(colBlk + trow) * K + k0 + schk;
        __builtin_amdgcn_global_load_lds((gas_t)gB,
                (las_t)(ab + 16384 + wv * 1024), 16, 0, 0);
    };

    auto compute = [&](int buf) {
        const u16* Ab = smem + buf * 12288;      // [256][32] (chunk-swizzled)
        const u16* Bb = Ab + 8192;               // [128][32]
        int cs = (quad ^ swz) * 8;
        bf16x8 af[4], bfv[4];
#pragma unroll
        for (int i = 0; i < 4; i++)
            af[i] = *(const bf16x8*)(Ab + (wr * 64 + i * 16 + m16) * 32 + cs);
#pragma unroll
        for (int i = 0; i < 4; i++)
            bfv[i] = *(const bf16x8*)(Bb + (wc * 64 + i * 16 + m16) * 32 + cs);
        __builtin_amdgcn_s_setprio(1);
#pragma unroll
        for (int im = 0; im < 4; im++)
#pragma unroll
            for (int in2 = 0; in2 < 4; in2++)
                acc[im][in2] = mfma16(af[im], bfv[in2], acc[im][in2]);
        __builtin_amdgcn_s_setprio(0);
    };

    stage(0, 0);
    stage(1, 32);
    int nt = K >> 5;
    int cb = 0, sb = 2;
    for (int t = 0; t < nt - 1; t++) {
        VM_WAIT_LG(3);                   // tile t landed; tile t+1 may fly;
        __builtin_amdgcn_s_barrier();    // no LDS reads in flight past here
        asm volatile("" ::: "memory");
        if (t + 2 < nt) stage(sb, (t + 2) << 5);
        compute(cb);
        cb = (cb == 2) ? 0 : cb + 1;
        sb = (sb == 2) ? 0 : sb + 1;
    }
    VM_WAIT_LG(0);
    __builtin_amdgcn_s_barrier();
    asm volatile("" ::: "memory");
    compute(cb);

#pragma unroll
    for (int in2 = 0; in2 < 4; in2++) {
        int gcol = colBlk + wc * 64 + in2 * 16 + m16;
        float bb = bias ? bias[gcol] : 0.f;
#pragma unroll
        for (int im = 0; im < 4; im++) {
            int growb = rowBlk + wr * 64 + im * 16 + quad * 4;
#pragma unroll
            for (int r = 0; r < 4; r++) {
                float vv = acc[im][in2][r] + bb;
                if (ACT == 1) vv = sigmoidf_(vv);
                if (ACT == 2) vv = fmaxf(vv, 0.f);
                if (ACT == 3 && gcol < 1024) vv *= 0.08838834764831845f;
                long grow = growb + r;
                if (RES) vv += res[grow * ldRes + gcol];
                if (OUTF32) ((float*)Out)[grow * ldOut + colOff + gcol] = vv;
                else        ((u16*)Out)[grow * ldOut + colOff + gcol] = f2bf(vv);
            }
        }
    }
}

// ---------------------------------------------------------------------------
// Flash attention v6 (verified R11 run, 741.4 us total): v4 body (4 waves x
// 32 q-rows, mt=2 fragment reuse, 80 KB LDS, 2 blk/CU) + counted-vmcnt
// double-barrier + setprio.  UNCHANGED.
// ---------------------------------------------------------------------------
__global__ __launch_bounds__(256, 2) void flash_attn(const u16* __restrict__ qkv,
        const u16* __restrict__ vt, u16* __restrict__ ctx) {
    constexpr int S = 2048, HD = 128, KT = 64, LD = 3072;
    __shared__ u16 Ks[2][KT * 128];   // [krow][chunk^swz] 16 KB each
    __shared__ u16 Vt[2][HD * 64];    // [dh][chunk^swz]  16 KB each
    __shared__ u16 Pa[128 * 64];      // [qrow][chunk^swz] 16 KB

    int bid = blockIdx.x;
    int bh = ((bid & 7) << 2) | ((bid >> 3) & 3);
    int qt = bid >> 5;
    int b = bh >> 3, h = bh & 7;
    int tid = threadIdx.x, wv = tid >> 6, lane = tid & 63;
    int m16 = lane & 15, quad = lane >> 4;
    long rowBase = (long)b * S;
    const u16* kptr = qkv + 1024 + h * HD;
    const u16* vptr = vt + (long)bh * HD * S;

    int kLR = lane >> 4, kCk = lane & 15;
    int vLR = lane >> 3, vCk = lane & 7;

    bf16x8 qf[2][4];
    int qrow0 = qt * 128 + wv * 32;
#pragma unroll
    for (int mt = 0; mt < 2; mt++)
#pragma unroll
        for (int kc = 0; kc < 4; kc++)
            qf[mt][kc] = *(const bf16x8*)(qkv + (rowBase + qrow0 + mt * 16 + m16) * LD
                                            + h * HD + kc * 32 + quad * 8);

    floatx4 o[2][8];
#pragma unroll
    for (int mt = 0; mt < 2; mt++)
#pragma unroll
        for (int dt = 0; dt < 8; dt++) o[mt][dt] = (floatx4){0.f, 0.f, 0.f, 0.f};
    float lsum[2][4];
#pragma unroll
    for (int mt = 0; mt < 2; mt++)
#pragma unroll
        for (int r = 0; r < 4; r++) lsum[mt][r] = 0.f;

    auto stage = [&](int buf, int krow0) {   // 8 global_load_lds per wave
#pragma unroll
        for (int it = 0; it < 4; it++) {
            int grl = wv * 16 + it * 4 + kLR;
            int gc = (kCk & 8) | ((kCk ^ grl) & 7);
            const u16* gK = kptr + (rowBase + krow0 + grl) * LD + gc * 8;
            __builtin_amdgcn_global_load_lds((gas_t)gK,
                    (las_t)&Ks[buf][(wv * 16 + it * 4) * 128], 16, 0, 0);
            int gvl = wv * 32 + it * 8 + vLR;
            int gvc = vCk ^ (gvl & 7);
            const u16* gV = vptr + (long)gvl * S + krow0 + gvc * 8;
            __builtin_amdgcn_global_load_lds((gas_t)gV,
                    (las_t)&Vt[buf][(wv * 32 + it * 8) * 64], 16, 0, 0);
        }
    };

    stage(0, 0);
    for (int kt = 0; kt < S / KT; kt++) {
        int cur = kt & 1;
        // barrier #1: every wave's LDS reads of buf[cur^1] are retired
        asm volatile("s_waitcnt lgkmcnt(0)" ::: "memory");
        __builtin_amdgcn_s_barrier();
        asm volatile("" ::: "memory");
        if (kt + 1 < S / KT) {
            stage(cur ^ 1, (kt + 1) * KT);
            VM_WAIT_LG(8);               // tile kt landed; kt+1's 8 in flight
        } else {
            VM_WAIT_LG(0);
        }
        __builtin_amdgcn_s_barrier();    // collective: tile kt resident
        asm volatile("" ::: "memory");

        floatx4 sacc[2][4];
#pragma unroll
        for (int mt = 0; mt < 2; mt++)
#pragma unroll
            for (int nt = 0; nt < 4; nt++) sacc[mt][nt] = (floatx4){0.f, 0.f, 0.f, 0.f};
        __builtin_amdgcn_s_setprio(1);
#pragma unroll
        for (int nt = 0; nt < 4; nt++)
#pragma unroll
            for (int kc = 0; kc < 4; kc++) {
                int c = kc * 4 + quad;
                int csw = (c & 8) | ((c ^ m16) & 7);
                bf16x8 kf = *(const bf16x8*)&Ks[cur][(nt * 16 + m16) * 128 + csw * 8];
                sacc[0][nt] = mfma16(qf[0][kc], kf, sacc[0][nt]);
                sacc[1][nt] = mfma16(qf[1][kc], kf, sacc[1][nt]);
            }
        __builtin_amdgcn_s_setprio(0);

#pragma unroll
        for (int mt = 0; mt < 2; mt++)
#pragma unroll
            for (int r = 0; r < 4; r++) {
                float ps = 0.f;
#pragma unroll
                for (int nt = 0; nt < 4; nt++) {
                    float pp = __expf(sacc[mt][nt][r]);
                    sacc[mt][nt][r] = pp;
                    ps += pp;
                }
                lsum[mt][r] += ps;
            }

#pragma unroll
        for (int mt = 0; mt < 2; mt++)
#pragma unroll
            for (int nt = 0; nt < 4; nt++)
#pragma unroll
                for (int r = 0; r < 4; r++) {
                    int qr = quad * 4 + r;
                    int c = nt * 2 + (m16 >> 3);
                    Pa[(wv * 32 + mt * 16 + qr) * 64 + ((c ^ (qr & 7)) * 8) + (m16 & 7)] =
                        f2bf(sacc[mt][nt][r]);
                }

        bf16x8 pf[2][2];
#pragma unroll
        for (int mt = 0; mt < 2; mt++)
#pragma unroll
            for (int kc = 0; kc < 2; kc++) {
                int c = kc * 4 + quad;
                int csw = (c ^ m16) & 7;
                pf[mt][kc] = *(const bf16x8*)&Pa[(wv * 32 + mt * 16 + m16) * 64 + csw * 8];
            }
        __builtin_amdgcn_s_setprio(1);
#pragma unroll
        for (int dt = 0; dt < 8; dt++)
#pragma unroll
            for (int kc = 0; kc < 2; kc++) {
                int c = kc * 4 + quad;
                int csw = (c ^ m16) & 7;
                bf16x8 vf = *(const bf16x8*)&Vt[cur][(dt * 16 + m16) * 64 + csw * 8];
                o[0][dt] = mfma16(pf[0][kc], vf, o[0][dt]);
                o[1][dt] = mfma16(pf[1][kc], vf, o[1][dt]);
            }
        __builtin_amdgcn_s_setprio(0);
    }

#pragma unroll
    for (int mt = 0; mt < 2; mt++) {
        float linv[4];
#pragma unroll
        for (int r = 0; r < 4; r++) {
            float rs = lsum[mt][r];
#pragma unroll
            for (int off = 1; off < 16; off <<= 1)
                rs += __shfl_xor(rs, off, 64);
            linv[r] = 1.f / rs;
        }
#pragma unroll
        for (int dt = 0; dt < 8; dt++)
#pragma unroll
            for (int r = 0; r < 4; r++) {
                float val = o[mt][dt][r] * linv[r];
                long grow = qt * 128 + wv * 32 + mt * 16 + quad * 4 + r;
                ctx[(rowBase + grow) * 1024 + h * HD + dt * 16 + m16] = f2bf(val);
            }
    }
}

// ---------------------------------------------------------------------------
// Launch.  Workspace map (MB offsets, lifetimes serial on stream):
//   [  0, 32) conc (u16 8192x2048)
//   [ 32, 48) slot1: xn -> ctx -> xn2
//   [ 48, 64) xn1 -> vt (16 MB) -> ffn1h low half
//   [ 64,112) gate (64..80) -> qkv (48 MB) -> {ffn1h high [64,80), x2 [80,112)}
//   [112,118) wscr: transposed weights (max 6 MB, merged QKV)
//   [118,~120) bias3 + delta + Btb + h_all
// ---------------------------------------------------------------------------
extern "C" void kernel_launch(void* const* d_in, const int* in_sizes, int n_in,
                              void* d_out, int out_size, void* d_ws, size_t ws_size,
                              hipStream_t stream) {
    (void)in_sizes; (void)n_in; (void)out_size; (void)ws_size;
    const float* x      = (const float*)d_in[0];
    const float* ln_g   = (const float*)d_in[1];
    const float* ln_b   = (const float*)d_in[2];
    const float* Wdelta = (const float*)d_in[3];
    const float* bdelta = (const float*)d_in[4];
    const float* Win    = (const float*)d_in[5];
    const float* b_in   = (const float*)d_in[6];
    const float* Wgate  = (const float*)d_in[7];
    const float* bgate  = (const float*)d_in[8];
    const float* Amat   = (const float*)d_in[9];
    const float* Cmat   = (const float*)d_in[10];
    const float* ln1_g  = (const float*)d_in[11];
    const float* ln1_b  = (const float*)d_in[12];
    const float* Wq     = (const float*)d_in[13];
    const float* bq     = (const float*)d_in[14];
    const float* Wk     = (const float*)d_in[15];
    const float* bk     = (const float*)d_in[16];
    const float* Wv     = (const float*)d_in[17];
    const float* bv     = (const float*)d_in[18];
    const float* Wo     = (const float*)d_in[19];
    const float* bo     = (const float*)d_in[20];
    const float* ln2_g  = (const float*)d_in[21];
    const float* ln2_b  = (const float*)d_in[22];
    const float* W1     = (const float*)d_in[23];
    const float* b1     = (const float*)d_in[24];
    const float* W2     = (const float*)d_in[25];
    const float* b2     = (const float*)d_in[26];
    const float* Wf     = (const float*)d_in[27];
    const float* bfp    = (const float*)d_in[28];
    const float* lnf_g  = (const float*)d_in[29];
    const float* lnf_b  = (const float*)d_in[30];

    char* base = (char*)d_ws;
    const size_t MB = 1u << 20;
    u16*   conc  = (u16*)(base + 0 * MB);
    u16*   slot1 = (u16*)(base + 32 * MB);
    u16*   xn1   = (u16*)(base + 48 * MB);
    u16*   qkv   = (u16*)(base + 64 * MB);
    u16*   wscr  = (u16*)(base + 112 * MB);
    float* bias3 = (float*)(base + 118 * MB);
    float* delta = (float*)(base + 118 * MB + 512 * 1024);
    float* Btb   = (float*)(base + 119 * MB);
    float* h_all = (float*)(base + 119 * MB + 512 * 1024);

    u16* xn    = slot1;
    u16* gate  = qkv;                        // dead before qkv written
    u16* ctx   = slot1;
    u16* xn2   = slot1;
    u16* vt    = xn1;                        // 16 MB, after xn1 consumed
    u16* ffn1h = xn1;                        // 32 MB: [48,80)
    float* x2  = (float*)(base + 80 * MB);   // 32 MB f32: [80,112)

    // 1) dual LN
    ln_dual_kernel<<<8192, 256, 0, stream>>>(x, ln_g, ln_b, ln1_g, ln1_b, xn, xn1);

    // 2) mamba projections (MFMA) + chunk-parallel scan
    delta_bt_kernel<<<128, 256, 0, stream>>>(xn, Wdelta, bdelta, Win, b_in, delta, Btb);
    scan_kernel<<<16, 256, 0, stream>>>(delta, Btb, Amat, h_all);

    // 3) gate = sigmoid(xn @ Wgate + bgate)   (256 WGs)
    transpose_cast<<<dim3(32, 32), 256, 0, stream>>>(Wgate, wscr, 1024, 1024, 0, 0);
    gemm_bt<1, 0, 0><<<dim3(8, 32), 512, 0, stream>>>(xn, wscr, bgate, nullptr,
            gate, 8192, 1024, 1024, 0, 1024, 0);
    // 4) mamba_out -> concat[:, :1024]
    mamba_out_kernel<<<8192, 256, 0, stream>>>(h_all, Cmat, gate, x, conc);

    // 5) merged QKV (Q cols pre-scaled by 1/sqrt(128) in epilogue, ACT=3) (768 WGs)
    transpose_cast<<<dim3(32, 32), 256, 0, stream>>>(Wq, wscr, 1024, 1024, 0, 0);
    transpose_cast<<<dim3(32, 32), 256, 0, stream>>>(Wk, wscr + 1024 * 1024, 1024, 1024, 0, 0);
    transpose_cast<<<dim3(32, 32), 256, 0, stream>>>(Wv, wscr + 2 * 1024 * 1024, 1024, 1024, 0, 0);
    concat_bias<<<12, 256, 0, stream>>>(bq, bk, bv, bias3);
    gemm_bt<3, 0, 0><<<dim3(24, 32), 512, 0, stream>>>(xn1, wscr, bias3, nullptr,
            qkv, 8192, 3072, 1024, 0, 3072, 0);

    // 5b) V -> vt[bh][dh][S] (xn1 dead after QKV GEMM)
    transpose_v<<<dim3(32, 2, 32), 256, 0, stream>>>(qkv, vt);

    // 6) attention (ctx overwrites xn in slot1)
    flash_attn<<<512, 256, 0, stream>>>(qkv, vt, ctx);

    // 7) x2 = x + ctx @ Wo + bo (f32; overwrites dead parts of qkv)
    transpose_cast<<<dim3(32, 32), 256, 0, stream>>>(Wo, wscr, 1024, 1024, 0, 0);
    gemm_bt<0, 1, 1><<<dim3(8, 32), 512, 0, stream>>>(ctx, wscr, bo, x,
            x2, 8192, 1024, 1024, 1024, 1024, 0);

    // 8) xn2 = LN(x2) -> bf16 (overwrites ctx)
    ln_one_kernel<1><<<8192, 256, 0, stream>>>(x2, ln2_g, ln2_b, xn2);

    // 9) FFN in two N-halves (ffn1h 32 MB reused)   (512 / 256 WGs)
    transpose_cast<<<dim3(64, 32), 256, 0, stream>>>(W1, wscr, 1024, 4096, 0, 0);
    gemm_bt<2, 0, 0><<<dim3(16, 32), 512, 0, stream>>>(xn2, wscr, b1, nullptr,
            ffn1h, 8192, 2048, 1024, 0, 2048, 0);
    transpose_cast<<<dim3(32, 64), 256, 0, stream>>>(W2, wscr, 2048, 1024, 0, 0);
    gemm_bt<0, 1, 1><<<dim3(8, 32), 512, 0, stream>>>(ffn1h, wscr, b2, x2,
            x2, 8192, 1024, 2048, 1024, 1024, 0);
    transpose_cast<<<dim3(64, 32), 256, 0, stream>>>(W1, wscr, 1024, 4096, 0, 2048);
    gemm_bt<2, 0, 0><<<dim3(16, 32), 512, 0, stream>>>(xn2, wscr, b1 + 2048, nullptr,
            ffn1h, 8192, 2048, 1024, 0, 2048, 0);
    transpose_cast<<<dim3(32, 64), 256, 0, stream>>>(W2, wscr, 2048, 1024, 2048, 0);
    gemm_bt<0, 1, 0><<<dim3(8, 32), 512, 0, stream>>>(ffn1h, wscr, nullptr, x2,
            conc, 8192, 1024, 2048, 1024, 2048, 1024);

    // 10) fused_pre = concat @ Wf + bf  (K=2048, f32 into d_out)
    transpose_cast<<<dim3(32, 64), 256, 0, stream>>>(Wf, wscr, 2048, 1024, 0, 0);
    gemm_bt<0, 0, 1><<<dim3(8, 32), 512, 0, stream>>>(conc, wscr, bfp, nullptr,
            (float*)d_out, 8192, 1024, 2048, 0, 1024, 0);

    // 11) final LN in place on d_out (f32)
    ln_one_kernel<0><<<8192, 256, 0, stream>>>((const float*)d_out, lnf_g, lnf_b, d_out);
}